// Round 2
// baseline (3053.207 us; speedup 1.0000x reference)
//
#include <hip/hip_runtime.h>
#include <stdint.h>

#define N_NODES 50000
#define N_EDGES 800000
#define NODE_TILES 782              // ceil(50000/64)

#define SE   72    // e-tile stride (bf16)
#define SW2  72
#define SPQ  136   // pq kernel strides (K=128)
#define SN1  200   // Wn1T row stride (K=192)
#define SN2  264   // Wn2T row stride (K=256)
#define SH1  264   // h1 LDS tile stride
#define ATS  32    // edge A-tile row stride (K=32, k>=16 zero)

typedef short bf16x8 __attribute__((ext_vector_type(8)));
typedef short short4v __attribute__((ext_vector_type(4)));
typedef unsigned short ushort8 __attribute__((ext_vector_type(8)));
typedef float f32x4  __attribute__((ext_vector_type(4)));

static __device__ __forceinline__ unsigned short f2bf(float f) {
  unsigned int x = __float_as_uint(f);
  unsigned int r = (x + 0x7fffu + ((x >> 16) & 1u)) >> 16;
  return (unsigned short)r;
}
static __device__ __forceinline__ float bf2f(unsigned short u) {
  return __uint_as_float(((unsigned int)u) << 16);
}
// silu via v_rcp_f32: avoids the full-precision fdiv expansion
static __device__ __forceinline__ float silu_f(float x) {
  return x * __builtin_amdgcn_rcpf(1.0f + __expf(-x));
}
static __device__ __forceinline__ float sigmoid_f(float x) {
  return __builtin_amdgcn_rcpf(1.0f + __expf(-x));
}
static __device__ __forceinline__ unsigned int cvt_pk_bf16(float lo, float hi) {
  unsigned int r;
  asm("v_cvt_pk_bf16_f32 %0, %1, %2" : "=v"(r) : "v"(lo), "v"(hi));
  return r;
}
static __device__ __forceinline__ bf16x8 pack8(float4 u, float4 v) {
  bf16x8 w;
  w[0] = (short)f2bf(u.x); w[1] = (short)f2bf(u.y);
  w[2] = (short)f2bf(u.z); w[3] = (short)f2bf(u.w);
  w[4] = (short)f2bf(v.x); w[5] = (short)f2bf(v.y);
  w[6] = (short)f2bf(v.z); w[7] = (short)f2bf(v.w);
  return w;
}

// ---------------------------------------------------------------------------
// prep: natural transposed bf16 weights + destination histogram.
// WrT: 64 x 32 bf16 B-operand for the rank-10+bias tail of layer 1.
// ---------------------------------------------------------------------------
__global__ void prep_hist(
    const int* __restrict__ eidx,
    const float* __restrict__ We1, const float* __restrict__ be1,
    const float* __restrict__ We2,
    const float* __restrict__ Wn1, const float* __restrict__ Wn2,
    unsigned short* __restrict__ WpqT, unsigned short* __restrict__ We2T,
    unsigned short* __restrict__ Wn1T, unsigned short* __restrict__ Wn2T,
    unsigned short* __restrict__ WrT,
    int* __restrict__ cnt)
{
  const int gid = blockIdx.x * 256 + threadIdx.x;
  const int gsz = gridDim.x * 256;
  for (int i = gid; i < 128 * SPQ; i += gsz) {
    int n = i / SPQ, k = i % SPQ;
    unsigned short v = 0;
    if (k < 128) v = (n < 64) ? f2bf(We1[k * 64 + n]) : f2bf(We1[(128 + k) * 64 + (n - 64)]);
    WpqT[i] = v;
  }
  for (int i = gid; i < 64 * SW2; i += gsz) {
    int n = i / SW2, k = i % SW2;
    We2T[i] = (k < 64) ? f2bf(We2[k * 64 + n]) : (unsigned short)0;
  }
  for (int i = gid; i < 256 * SN1; i += gsz) {
    int n = i / SN1, k = i % SN1;
    Wn1T[i] = (k < 192) ? f2bf(Wn1[k * 256 + n]) : (unsigned short)0;
  }
  for (int i = gid; i < 128 * SN2; i += gsz) {
    int n = i / SN2, k = i % SN2;
    Wn2T[i] = (k < 256) ? f2bf(Wn2[k * 128 + n]) : (unsigned short)0;
  }
  for (int i = gid; i < 64 * 32; i += gsz) {
    int n = i >> 5, k = i & 31;
    float v = 0.f;
    if (k < 2)       v = We1[256 * 64 + n];
    else if (k < 4)  v = We1[257 * 64 + n];
    else if (k < 12) v = We1[(258 + (k - 4)) * 64 + n];
    else if (k == 12) v = be1[n];
    else if (k == 13) { float w = We1[256 * 64 + n]; v = w - bf2f(f2bf(w)); }
    else if (k == 14) { float w = We1[257 * 64 + n]; v = w - bf2f(f2bf(w)); }
    else if (k == 15) { float w = be1[n];            v = w - bf2f(f2bf(w)); }
    WrT[i] = (k < 16) ? f2bf(v) : (unsigned short)0;
  }
  if (gid < N_EDGES) atomicAdd(&cnt[eidx[gid]], 1);
}

// ---------------------------------------------------------------------------
// scan: exclusive prefix of cnt -> rowptr[50001], cursor copy. 1 block.
// ---------------------------------------------------------------------------
__global__ __launch_bounds__(1024) void scan_kernel(
    const int* __restrict__ cnt, int* __restrict__ rowptr,
    int* __restrict__ cursor)
{
  __shared__ int wsum[16], woff[16];
  const int t = threadIdx.x;
  const int lane = t & 63, wid = t >> 6;
  const int base = t * 49;
  int loc[49];
  int s = 0;
  #pragma unroll
  for (int i = 0; i < 49; ++i) {
    int idx = base + i;
    int c = (idx < N_NODES) ? cnt[idx] : 0;
    loc[i] = s; s += c;
  }
  int v = s;
  #pragma unroll
  for (int o = 1; o < 64; o <<= 1) {
    int u = __shfl_up(v, o);
    if (lane >= o) v += u;
  }
  if (lane == 63) wsum[wid] = v;
  __syncthreads();
  if (t == 0) {
    int a = 0;
    for (int w = 0; w < 16; ++w) { woff[w] = a; a += wsum[w]; }
    rowptr[N_NODES] = a;
  }
  __syncthreads();
  const int texcl = woff[wid] + (v - s);
  #pragma unroll
  for (int i = 0; i < 49; ++i) {
    int idx = base + i;
    if (idx < N_NODES) {
      int r = texcl + loc[i];
      rowptr[idx] = r;
      cursor[idx] = r;
    }
  }
}

// ---------------------------------------------------------------------------
// fill: order[slot] = edge id (4-B scatter only).
// ---------------------------------------------------------------------------
__global__ void fill_kernel(const int* __restrict__ eidx,
                            int* __restrict__ cursor, int* __restrict__ order)
{
  int e = blockIdx.x * 256 + threadIdx.x;
  if (e < N_EDGES) {
    int d = eidx[e];
    int pos = atomicAdd(&cursor[d], 1);
    order[pos] = e;
  }
}

// ---------------------------------------------------------------------------
// reorder: one thread per CSR slot. Gathers per-edge metadata into slot order;
// computes d2/delta + gate MLP here.
// ---------------------------------------------------------------------------
__global__ void reorder_kernel(
    const int* __restrict__ eidx, const float* __restrict__ xyz,
    const float* __restrict__ estruct, const float* __restrict__ erest,
    const int* __restrict__ order,
    const float* __restrict__ Wg1, const float* __restrict__ bg1,
    const float* __restrict__ Wg2, const float* __restrict__ bg2,
    float4* __restrict__ metaA, unsigned short* __restrict__ sst,
    int* __restrict__ in_s)
{
  int s = blockIdx.x * 256 + threadIdx.x;
  if (s >= N_EDGES) return;
  int e = order[s];
  int i = eidx[e], j = eidx[N_EDGES + e];
  float dx = xyz[i * 3 + 0] - xyz[j * 3 + 0];
  float dy = xyz[i * 3 + 1] - xyz[j * 3 + 1];
  float dz = xyz[i * 3 + 2] - xyz[j * 3 + 2];
  float d2 = dx * dx + dy * dy + dz * dz;
  float dist = sqrtf(d2 + 1e-9f);
  float rest = erest[e];
  float dl = (dist - rest) / (rest + 1e-9f);
  float4 s0 = *(const float4*)&estruct[e * 8];
  float4 s1 = *(const float4*)&estruct[e * 8 + 4];
  float st[8] = {s0.x, s0.y, s0.z, s0.w, s1.x, s1.y, s1.z, s1.w};
  float gsum = 0.f;
  #pragma unroll
  for (int h = 0; h < 32; ++h) {
    float a = bg1[h] + d2 * Wg1[0 * 32 + h] + dl * Wg1[1 * 32 + h];
    #pragma unroll
    for (int c = 0; c < 8; ++c) a += st[c] * Wg1[(2 + c) * 32 + h];
    gsum += silu_f(a) * Wg2[h];
  }
  float g = sigmoid_f(gsum + bg2[0]);
  metaA[s] = make_float4(d2, dl, g, __int_as_float(j));
  ushort8 w;
  #pragma unroll
  for (int c = 0; c < 8; ++c) w[c] = f2bf(st[c]);
  *(ushort8*)&sst[(long)s * 8] = w;
  in_s[s] = i;
}

// ---------------------------------------------------------------------------
// pq: [P|Q] = H @ [We1[0:128] | We1[128:256]], bf16, natural layout.
// Also exports the bf16-converted H tile to Hbf (reused by node_fused).
// ---------------------------------------------------------------------------
__global__ __launch_bounds__(256, 2) void pq_kernel(
    const float* __restrict__ H, const unsigned short* __restrict__ WpqT,
    unsigned short* __restrict__ P, unsigned short* __restrict__ Q,
    unsigned short* __restrict__ Hbf)
{
  __shared__ unsigned short As[64 * SPQ];
  __shared__ unsigned short Ws[128 * SPQ];

  const int tid  = threadIdx.x;
  const int lane = tid & 63;
  const int wv   = tid >> 6;
  const int lr   = lane & 15;
  const int lq   = lane >> 4;
  const int m0   = wv * 16;
  const int n0   = blockIdx.x * 64;

  for (int i = tid * 8; i < 128 * SPQ; i += 256 * 8)
    *(bf16x8*)&Ws[i] = *(const bf16x8*)&WpqT[i];
  {
    int le = tid >> 2, q = tid & 3;
    int node = n0 + le; if (node >= N_NODES) node = N_NODES - 1;
    const float* src = H + (long)node * 128 + q * 32;
    unsigned short* dst = &As[le * SPQ + q * 32];
    #pragma unroll
    for (int c = 0; c < 32; c += 8) {
      float4 u = *(const float4*)(src + c);
      float4 v = *(const float4*)(src + c + 4);
      *(bf16x8*)(dst + c) = pack8(u, v);
    }
  }
  __syncthreads();

  // export bf16 H tile (coalesced 16B stores from LDS)
  for (int idx = tid * 8; idx < 64 * 128; idx += 256 * 8) {
    int row = idx >> 7, col = idx & 127;
    *(bf16x8*)&Hbf[((long)n0 + row) * 128 + col] = *(const bf16x8*)&As[row * SPQ + col];
  }

  f32x4 zero4 = {0.f, 0.f, 0.f, 0.f};
  f32x4 acc[8];
  #pragma unroll
  for (int f = 0; f < 8; ++f) acc[f] = zero4;
  #pragma unroll
  for (int s = 0; s < 4; ++s) {
    int kb = s * 32 + lq * 8;
    bf16x8 a = *(const bf16x8*)&As[(m0 + lr) * SPQ + kb];
    #pragma unroll
    for (int f = 0; f < 8; ++f) {
      bf16x8 b = *(const bf16x8*)&Ws[(f * 16 + lr) * SPQ + kb];
      acc[f] = __builtin_amdgcn_mfma_f32_16x16x32_bf16(a, b, acc[f], 0, 0, 0);
    }
  }
  #pragma unroll
  for (int f = 0; f < 8; ++f) {
    #pragma unroll
    for (int r = 0; r < 4; ++r) {
      int node = n0 + m0 + lq * 4 + r;
      if (node < N_NODES) {
        if (f < 4) P[(long)node * 64 + f * 16 + lr] = f2bf(acc[f][r]);
        else       Q[(long)node * 64 + (f - 4) * 16 + lr] = f2bf(acc[f][r]);
      }
    }
  }
}

// ---------------------------------------------------------------------------
// edge_compute (R7): messages accumulated straight into agg[node][64] via
// f32 global atomics -- kills the 102 MB em intermediate AND node_fused's
// latency-bound CSR walk. Slot-sorted edges keep atomic lines wave-local.
// ---------------------------------------------------------------------------
__global__ __launch_bounds__(256, 4) void edge_compute(
    const unsigned short* __restrict__ P, const unsigned short* __restrict__ Q,
    const int* __restrict__ in_s,
    const float4* __restrict__ metaA, const unsigned short* __restrict__ sst,
    const unsigned short* __restrict__ We2T, const float* __restrict__ be2,
    const unsigned short* __restrict__ WrT,
    float* __restrict__ agg)
{
  __shared__ unsigned short W2s[64 * SW2];      // 9.2 KB
  __shared__ unsigned short Es [4 * 16 * SE];   // 9.2 KB
  __shared__ unsigned short At [4 * 16 * ATS];  // 4.0 KB

  const int tid  = threadIdx.x;
  const int lane = tid & 63;
  const int wv   = tid >> 6;
  const int lr   = lane & 15;
  const int lq   = lane >> 4;

  for (int i = tid * 8; i < 64 * SW2; i += 256 * 8)
    *(bf16x8*)&W2s[i] = *(const bf16x8*)&We2T[i];

  unsigned short* Es_w = &Es[wv * 16 * SE];
  unsigned short* At_w = &At[wv * 16 * ATS];

  if (lane < 16) {
    ushort8 z;
    #pragma unroll
    for (int c = 0; c < 8; ++c) z[c] = 0;
    *(ushort8*)&At_w[lane * ATS + 16] = z;
    *(ushort8*)&At_w[lane * ATS + 24] = z;
  }

  bf16x8 aWr[4];
  float bias2[4][4];
  #pragma unroll
  for (int f = 0; f < 4; ++f) {
    aWr[f] = *(const bf16x8*)&WrT[(f * 16 + lr) * 32 + lq * 8];
    #pragma unroll
    for (int r = 0; r < 4; ++r) bias2[f][r] = be2[f * 16 + lq * 4 + r];
  }
  __syncthreads();

  f32x4 zero4 = {0.f, 0.f, 0.f, 0.f};
  const int n_tiles = N_EDGES / 16;  // 50000
  for (int tile = blockIdx.x * 4 + wv; tile < n_tiles; tile += gridDim.x * 4) {
    const int s0 = tile * 16;

    float4 mm = metaA[s0 + lr];
    int   inode = in_s[s0 + lr];
    int   jnode = __float_as_int(mm.w);
    float g     = mm.z;

    if (lane < 16) {
      ushort8 sv = *(const ushort8*)&sst[(long)(s0 + lane) * 8];
      float d2 = mm.x, dl = mm.y;
      unsigned short d2h = f2bf(d2);
      unsigned short d2l = f2bf(d2 - bf2f(d2h));
      unsigned short dlh = f2bf(dl);
      unsigned short dll = f2bf(dl - bf2f(dlh));
      ushort8 w0, w1;
      w0[0] = d2h;   w0[1] = d2l;   w0[2] = dlh;   w0[3] = dll;
      w0[4] = sv[0]; w0[5] = sv[1]; w0[6] = sv[2]; w0[7] = sv[3];
      w1[0] = sv[4]; w1[1] = sv[5]; w1[2] = sv[6]; w1[3] = sv[7];
      w1[4] = 0x3F80u; w1[5] = d2h; w1[6] = dlh;  w1[7] = 0x3F80u;
      *(ushort8*)&At_w[lane * ATS]     = w0;
      *(ushort8*)&At_w[lane * ATS + 8] = w1;
    }

    // R = meta-tail @ Wr (+be1), output: n = f*16+lq*4+r, edge = lr
    bf16x8 bA = *(const bf16x8*)&At_w[lr * ATS + lq * 8];
    f32x4 acc1[4];
    #pragma unroll
    for (int f = 0; f < 4; ++f)
      acc1[f] = __builtin_amdgcn_mfma_f32_16x16x32_bf16(aWr[f], bA, zero4, 0, 0, 0);

    // finish layer 1: e = silu(P[i] + Q[j] + R)
    const unsigned short* Pb = P + (long)inode * 64;
    const unsigned short* Qb = Q + (long)jnode * 64;
    #pragma unroll
    for (int f = 0; f < 4; ++f) {
      short4v pv = *(const short4v*)&Pb[f * 16 + lq * 4];
      short4v qv = *(const short4v*)&Qb[f * 16 + lq * 4];
      float v0 = silu_f(bf2f((unsigned short)pv[0]) + bf2f((unsigned short)qv[0]) + acc1[f][0]);
      float v1 = silu_f(bf2f((unsigned short)pv[1]) + bf2f((unsigned short)qv[1]) + acc1[f][1]);
      float v2 = silu_f(bf2f((unsigned short)pv[2]) + bf2f((unsigned short)qv[2]) + acc1[f][2]);
      float v3 = silu_f(bf2f((unsigned short)pv[3]) + bf2f((unsigned short)qv[3]) + acc1[f][3]);
      uint2 w;
      w.x = cvt_pk_bf16(v0, v1);
      w.y = cvt_pk_bf16(v2, v3);
      *(uint2*)&Es_w[lr * SE + f * 16 + lq * 4] = w;
    }

    // layer 2: acc2[f][r] = (e @ We2)[edge lr][n = f*16+lq*4+r]
    f32x4 acc2[4];
    #pragma unroll
    for (int f = 0; f < 4; ++f) acc2[f] = zero4;
    #pragma unroll
    for (int s = 0; s < 2; ++s) {
      int kb = s * 32 + lq * 8;
      bf16x8 bE = *(const bf16x8*)&Es_w[lr * SE + kb];
      #pragma unroll
      for (int f = 0; f < 4; ++f) {
        bf16x8 aW = *(const bf16x8*)&W2s[(f * 16 + lr) * SW2 + kb];
        acc2[f] = __builtin_amdgcn_mfma_f32_16x16x32_bf16(aW, bE, acc2[f], 0, 0, 0);
      }
    }

    // epilogue: silu, gate, accumulate into agg via f32 atomics (un-rounded)
    float* ap = agg + (long)inode * 64 + lq * 4;
    #pragma unroll
    for (int f = 0; f < 4; ++f) {
      float o0 = silu_f(acc2[f][0] + bias2[f][0]) * g;
      float o1 = silu_f(acc2[f][1] + bias2[f][1]) * g;
      float o2 = silu_f(acc2[f][2] + bias2[f][2]) * g;
      float o3 = silu_f(acc2[f][3] + bias2[f][3]) * g;
      atomicAdd(&ap[f * 16 + 0], o0);
      atomicAdd(&ap[f * 16 + 1], o1);
      atomicAdd(&ap[f * 16 + 2], o2);
      atomicAdd(&ap[f * 16 + 3], o3);
    }
  }
}

// ---------------------------------------------------------------------------
// node_fused (R7): no CSR walk -- agg comes in dense f32. phase1 reads bf16
// Hbf (pre-converted by pq) + agg; phase2 upd + residual + LayerNorm.
// LDS 34 KB -> 4 blocks/CU; h1t is wave-private (no barrier needed).
// ---------------------------------------------------------------------------
__global__ __launch_bounds__(256, 4) void node_fused_kernel(
    const float* __restrict__ H, const unsigned short* __restrict__ Hbf,
    const float* __restrict__ agg,
    const unsigned short* __restrict__ Wn1T, const float* __restrict__ bn1,
    const unsigned short* __restrict__ Wn2T, const float* __restrict__ bn2,
    const float* __restrict__ ln_g, const float* __restrict__ ln_b,
    float* __restrict__ out)
{
  __shared__ unsigned short h1t[64 * SH1];  // 33.8 KB

  const int tid  = threadIdx.x;
  const int lane = tid & 63;
  const int wv   = tid >> 6;
  const int lr   = lane & 15;
  const int lq   = lane >> 4;
  const int m0   = wv * 16;
  const int n0   = blockIdx.x * 64;

  // ---- phase 1: h1 tile ----
  int rowa = n0 + m0 + lr;
  int rowc = rowa < N_NODES ? rowa : N_NODES - 1;

  f32x4 zero4 = {0.f, 0.f, 0.f, 0.f};
  f32x4 acc1[16];
  #pragma unroll
  for (int f = 0; f < 16; ++f) acc1[f] = zero4;
  #pragma unroll
  for (int s = 0; s < 6; ++s) {
    int kb = s * 32 + lq * 8;
    bf16x8 a;
    if (s < 4) {
      a = *(const bf16x8*)&Hbf[(long)rowa * 128 + kb];   // Hbf covers all tile rows
    } else {
      const float* p = agg + (long)rowc * 64 + (kb - 128);
      float4 u = *(const float4*)p;
      float4 v = *(const float4*)(p + 4);
      a = pack8(u, v);
    }
    #pragma unroll
    for (int f = 0; f < 16; ++f) {
      bf16x8 b = *(const bf16x8*)&Wn1T[(long)(f * 16 + lr) * SN1 + kb];
      acc1[f] = __builtin_amdgcn_mfma_f32_16x16x32_bf16(a, b, acc1[f], 0, 0, 0);
    }
  }
  #pragma unroll
  for (int f = 0; f < 16; ++f) {
    float bias = bn1[f * 16 + lr];
    #pragma unroll
    for (int r = 0; r < 4; ++r)
      h1t[(m0 + lq * 4 + r) * SH1 + f * 16 + lr] = f2bf(silu_f(acc1[f][r] + bias));
  }
  // h1t rows m0..m0+15 are written and read by this wave only: no barrier.

  // ---- phase 2: upd + residual + LayerNorm ----
  f32x4 acc2[8];
  #pragma unroll
  for (int f = 0; f < 8; ++f) acc2[f] = zero4;
  #pragma unroll
  for (int s = 0; s < 8; ++s) {
    int kb = s * 32 + lq * 8;
    bf16x8 a = *(const bf16x8*)&h1t[(m0 + lr) * SH1 + kb];
    #pragma unroll
    for (int f = 0; f < 8; ++f) {
      bf16x8 b = *(const bf16x8*)&Wn2T[(long)(f * 16 + lr) * SN2 + kb];
      acc2[f] = __builtin_amdgcn_mfma_f32_16x16x32_bf16(a, b, acc2[f], 0, 0, 0);
    }
  }

  #pragma unroll
  for (int r = 0; r < 4; ++r) {
    int node = n0 + m0 + lq * 4 + r;
    int nc = node < N_NODES ? node : N_NODES - 1;
    float x[8];
    float sum = 0.f, sumsq = 0.f;
    #pragma unroll
    for (int f = 0; f < 8; ++f) {
      int n = f * 16 + lr;
      float u = acc2[f][r] + bn2[n];
      float xv = H[(long)nc * 128 + n] + u;
      x[f] = xv;
      sum += xv;
      sumsq += xv * xv;
    }
    #pragma unroll
    for (int o = 1; o < 16; o <<= 1) {
      sum   += __shfl_xor(sum, o);
      sumsq += __shfl_xor(sumsq, o);
    }
    float mu  = sum * (1.f / 128.f);
    float var = sumsq * (1.f / 128.f) - mu * mu;
    float rstd = rsqrtf(var + 1e-5f);
    if (node < N_NODES) {
      #pragma unroll
      for (int f = 0; f < 8; ++f) {
        int n = f * 16 + lr;
        out[(long)node * 128 + n] = (x[f] - mu) * rstd * ln_g[n] + ln_b[n];
      }
    }
  }
}

extern "C" void kernel_launch(void* const* d_in, const int* in_sizes, int n_in,
                              void* d_out, int out_size, void* d_ws, size_t ws_size,
                              hipStream_t stream) {
  const float* H       = (const float*)d_in[0];
  const float* xyz     = (const float*)d_in[1];
  const int*   eidx    = (const int*)d_in[2];
  const float* estruct = (const float*)d_in[3];
  const float* erest   = (const float*)d_in[4];
  const float* We1     = (const float*)d_in[5];
  const float* be1     = (const float*)d_in[6];
  const float* We2     = (const float*)d_in[7];
  const float* be2     = (const float*)d_in[8];
  const float* Wg1     = (const float*)d_in[9];
  const float* bg1     = (const float*)d_in[10];
  const float* Wg2     = (const float*)d_in[11];
  const float* bg2     = (const float*)d_in[12];
  const float* Wn1     = (const float*)d_in[13];
  const float* bn1     = (const float*)d_in[14];
  const float* Wn2     = (const float*)d_in[15];
  const float* bn2     = (const float*)d_in[16];
  const float* ln_g    = (const float*)d_in[17];
  const float* ln_b    = (const float*)d_in[18];

  char* ws = (char*)d_ws;
  float*          agg    = (float*)(ws + 0);                    //  12,812,288 (50048*64*4)
  unsigned short* Hbf    = (unsigned short*)(ws + 12812288);    //  12,812,288 (50048*128*2)
  float4*         metaA  = (float4*)(ws + 25624576);            //  12,800,000
  unsigned short* sst    = (unsigned short*)(ws + 38424576);    //  12,800,000
  int*            in_s   = (int*)(ws + 51224576);               //   3,200,000
  int*            order  = (int*)(ws + 54424576);               //   3,200,000 (dead after reorder)
  unsigned short* P      = (unsigned short*)(ws + 54424576);    //   6,400,000 (aliases order)
  unsigned short* Qm     = (unsigned short*)(ws + 60824576);    //   6,400,000
  int*            cnt    = (int*)(ws + 67224576);               //     200,192
  int*            rowptr = (int*)(ws + 67424768);               //     200,192
  int*            cursor = (int*)(ws + 67624960);               //     200,192
  unsigned short* WpqT   = (unsigned short*)(ws + 67825152);    //      34,816
  unsigned short* We2T   = (unsigned short*)(ws + 67859968);    //       9,216
  unsigned short* Wn1T   = (unsigned short*)(ws + 67869184);    //     102,400
  unsigned short* Wn2T   = (unsigned short*)(ws + 67971584);    //      67,584
  unsigned short* WrT    = (unsigned short*)(ws + 68039168);    //       4,096
  float* out = (float*)d_out;

  hipMemsetAsync(cnt, 0, (size_t)N_NODES * sizeof(int), stream);
  hipMemsetAsync(agg, 0, (size_t)50048 * 64 * sizeof(float), stream);

  hipLaunchKernelGGL(prep_hist, dim3(3125), dim3(256), 0, stream,
                     eidx, We1, be1, We2, Wn1, Wn2, WpqT, We2T, Wn1T, Wn2T, WrT, cnt);
  hipLaunchKernelGGL(scan_kernel, dim3(1), dim3(1024), 0, stream,
                     cnt, rowptr, cursor);
  hipLaunchKernelGGL(fill_kernel, dim3(3125), dim3(256), 0, stream,
                     eidx, cursor, order);
  hipLaunchKernelGGL(reorder_kernel, dim3(3125), dim3(256), 0, stream,
                     eidx, xyz, estruct, erest, order,
                     Wg1, bg1, Wg2, bg2, metaA, sst, in_s);
  hipLaunchKernelGGL(pq_kernel, dim3(NODE_TILES), dim3(256), 0, stream,
                     H, WpqT, P, Qm, Hbf);
  hipLaunchKernelGGL(edge_compute, dim3(1024), dim3(256), 0, stream,
                     P, Qm, in_s, metaA, sst, We2T, be2, WrT, agg);
  hipLaunchKernelGGL(node_fused_kernel, dim3(NODE_TILES), dim3(256), 0, stream,
                     H, Hbf, agg, Wn1T, bn1, Wn2T, bn2, ln_g, ln_b, out);
}

// Round 3
// 472.065 us; speedup vs baseline: 6.4678x; 6.4678x over previous
//
#include <hip/hip_runtime.h>
#include <stdint.h>

#define N_NODES 50000
#define N_EDGES 800000
#define NODE_TILES 782              // ceil(50000/64)

#define SE   72    // e-tile stride (bf16)
#define SW2  72
#define SPQ  136   // pq kernel strides (K=128)
#define SN1  200   // Wn1T row stride (K=192)
#define SN2  264   // Wn2T row stride (K=256)
#define SH1  264   // h1 LDS tile stride
#define ATS  32    // edge A-tile row stride (K=32, k>=16 zero)
#define MSTR 68    // msg LDS row stride in f32 (64 + 4 pad: conflict-free both phases)

#define EC_GRID 962   // 962*4 waves * 13 tiles = 50024 >= 50000
#define EC_CHUNK 13

typedef short bf16x8 __attribute__((ext_vector_type(8)));
typedef short short4v __attribute__((ext_vector_type(4)));
typedef unsigned short ushort8 __attribute__((ext_vector_type(8)));
typedef float f32x4  __attribute__((ext_vector_type(4)));

static __device__ __forceinline__ unsigned short f2bf(float f) {
  unsigned int x = __float_as_uint(f);
  unsigned int r = (x + 0x7fffu + ((x >> 16) & 1u)) >> 16;
  return (unsigned short)r;
}
static __device__ __forceinline__ float bf2f(unsigned short u) {
  return __uint_as_float(((unsigned int)u) << 16);
}
// silu via v_rcp_f32: avoids the full-precision fdiv expansion
static __device__ __forceinline__ float silu_f(float x) {
  return x * __builtin_amdgcn_rcpf(1.0f + __expf(-x));
}
static __device__ __forceinline__ float sigmoid_f(float x) {
  return __builtin_amdgcn_rcpf(1.0f + __expf(-x));
}
static __device__ __forceinline__ unsigned int cvt_pk_bf16(float lo, float hi) {
  unsigned int r;
  asm("v_cvt_pk_bf16_f32 %0, %1, %2" : "=v"(r) : "v"(lo), "v"(hi));
  return r;
}
static __device__ __forceinline__ bf16x8 pack8(float4 u, float4 v) {
  bf16x8 w;
  w[0] = (short)f2bf(u.x); w[1] = (short)f2bf(u.y);
  w[2] = (short)f2bf(u.z); w[3] = (short)f2bf(u.w);
  w[4] = (short)f2bf(v.x); w[5] = (short)f2bf(v.y);
  w[6] = (short)f2bf(v.z); w[7] = (short)f2bf(v.w);
  return w;
}

// ---------------------------------------------------------------------------
// prep: natural transposed bf16 weights + destination histogram.
// WrT: 64 x 32 bf16 B-operand for the rank-10+bias tail of layer 1.
// ---------------------------------------------------------------------------
__global__ void prep_hist(
    const int* __restrict__ eidx,
    const float* __restrict__ We1, const float* __restrict__ be1,
    const float* __restrict__ We2,
    const float* __restrict__ Wn1, const float* __restrict__ Wn2,
    unsigned short* __restrict__ WpqT, unsigned short* __restrict__ We2T,
    unsigned short* __restrict__ Wn1T, unsigned short* __restrict__ Wn2T,
    unsigned short* __restrict__ WrT,
    int* __restrict__ cnt)
{
  const int gid = blockIdx.x * 256 + threadIdx.x;
  const int gsz = gridDim.x * 256;
  for (int i = gid; i < 128 * SPQ; i += gsz) {
    int n = i / SPQ, k = i % SPQ;
    unsigned short v = 0;
    if (k < 128) v = (n < 64) ? f2bf(We1[k * 64 + n]) : f2bf(We1[(128 + k) * 64 + (n - 64)]);
    WpqT[i] = v;
  }
  for (int i = gid; i < 64 * SW2; i += gsz) {
    int n = i / SW2, k = i % SW2;
    We2T[i] = (k < 64) ? f2bf(We2[k * 64 + n]) : (unsigned short)0;
  }
  for (int i = gid; i < 256 * SN1; i += gsz) {
    int n = i / SN1, k = i % SN1;
    Wn1T[i] = (k < 192) ? f2bf(Wn1[k * 256 + n]) : (unsigned short)0;
  }
  for (int i = gid; i < 128 * SN2; i += gsz) {
    int n = i / SN2, k = i % SN2;
    Wn2T[i] = (k < 256) ? f2bf(Wn2[k * 128 + n]) : (unsigned short)0;
  }
  for (int i = gid; i < 64 * 32; i += gsz) {
    int n = i >> 5, k = i & 31;
    float v = 0.f;
    if (k < 2)       v = We1[256 * 64 + n];
    else if (k < 4)  v = We1[257 * 64 + n];
    else if (k < 12) v = We1[(258 + (k - 4)) * 64 + n];
    else if (k == 12) v = be1[n];
    else if (k == 13) { float w = We1[256 * 64 + n]; v = w - bf2f(f2bf(w)); }
    else if (k == 14) { float w = We1[257 * 64 + n]; v = w - bf2f(f2bf(w)); }
    else if (k == 15) { float w = be1[n];            v = w - bf2f(f2bf(w)); }
    WrT[i] = (k < 16) ? f2bf(v) : (unsigned short)0;
  }
  if (gid < N_EDGES) atomicAdd(&cnt[eidx[gid]], 1);
}

// ---------------------------------------------------------------------------
// scan: exclusive prefix of cnt -> rowptr[50001], cursor copy. 1 block.
// ---------------------------------------------------------------------------
__global__ __launch_bounds__(1024) void scan_kernel(
    const int* __restrict__ cnt, int* __restrict__ rowptr,
    int* __restrict__ cursor)
{
  __shared__ int wsum[16], woff[16];
  const int t = threadIdx.x;
  const int lane = t & 63, wid = t >> 6;
  const int base = t * 49;
  int loc[49];
  int s = 0;
  #pragma unroll
  for (int i = 0; i < 49; ++i) {
    int idx = base + i;
    int c = (idx < N_NODES) ? cnt[idx] : 0;
    loc[i] = s; s += c;
  }
  int v = s;
  #pragma unroll
  for (int o = 1; o < 64; o <<= 1) {
    int u = __shfl_up(v, o);
    if (lane >= o) v += u;
  }
  if (lane == 63) wsum[wid] = v;
  __syncthreads();
  if (t == 0) {
    int a = 0;
    for (int w = 0; w < 16; ++w) { woff[w] = a; a += wsum[w]; }
    rowptr[N_NODES] = a;
  }
  __syncthreads();
  const int texcl = woff[wid] + (v - s);
  #pragma unroll
  for (int i = 0; i < 49; ++i) {
    int idx = base + i;
    if (idx < N_NODES) {
      int r = texcl + loc[i];
      rowptr[idx] = r;
      cursor[idx] = r;
    }
  }
}

// ---------------------------------------------------------------------------
// fill: order[slot] = edge id (4-B scatter only).
// ---------------------------------------------------------------------------
__global__ void fill_kernel(const int* __restrict__ eidx,
                            int* __restrict__ cursor, int* __restrict__ order)
{
  int e = blockIdx.x * 256 + threadIdx.x;
  if (e < N_EDGES) {
    int d = eidx[e];
    int pos = atomicAdd(&cursor[d], 1);
    order[pos] = e;
  }
}

// ---------------------------------------------------------------------------
// reorder: one thread per CSR slot. Gathers per-edge metadata into slot order;
// computes d2/delta + gate MLP here.
// ---------------------------------------------------------------------------
__global__ void reorder_kernel(
    const int* __restrict__ eidx, const float* __restrict__ xyz,
    const float* __restrict__ estruct, const float* __restrict__ erest,
    const int* __restrict__ order,
    const float* __restrict__ Wg1, const float* __restrict__ bg1,
    const float* __restrict__ Wg2, const float* __restrict__ bg2,
    float4* __restrict__ metaA, unsigned short* __restrict__ sst,
    int* __restrict__ in_s)
{
  int s = blockIdx.x * 256 + threadIdx.x;
  if (s >= N_EDGES) return;
  int e = order[s];
  int i = eidx[e], j = eidx[N_EDGES + e];
  float dx = xyz[i * 3 + 0] - xyz[j * 3 + 0];
  float dy = xyz[i * 3 + 1] - xyz[j * 3 + 1];
  float dz = xyz[i * 3 + 2] - xyz[j * 3 + 2];
  float d2 = dx * dx + dy * dy + dz * dz;
  float dist = sqrtf(d2 + 1e-9f);
  float rest = erest[e];
  float dl = (dist - rest) / (rest + 1e-9f);
  float4 s0 = *(const float4*)&estruct[e * 8];
  float4 s1 = *(const float4*)&estruct[e * 8 + 4];
  float st[8] = {s0.x, s0.y, s0.z, s0.w, s1.x, s1.y, s1.z, s1.w};
  float gsum = 0.f;
  #pragma unroll
  for (int h = 0; h < 32; ++h) {
    float a = bg1[h] + d2 * Wg1[0 * 32 + h] + dl * Wg1[1 * 32 + h];
    #pragma unroll
    for (int c = 0; c < 8; ++c) a += st[c] * Wg1[(2 + c) * 32 + h];
    gsum += silu_f(a) * Wg2[h];
  }
  float g = sigmoid_f(gsum + bg2[0]);
  metaA[s] = make_float4(d2, dl, g, __int_as_float(j));
  ushort8 w;
  #pragma unroll
  for (int c = 0; c < 8; ++c) w[c] = f2bf(st[c]);
  *(ushort8*)&sst[(long)s * 8] = w;
  in_s[s] = i;
}

// ---------------------------------------------------------------------------
// pq: [P|Q] = H @ [We1[0:128] | We1[128:256]], bf16, natural layout.
// Also exports the bf16-converted H tile to Hbf (reused by node_fused).
// ---------------------------------------------------------------------------
__global__ __launch_bounds__(256, 2) void pq_kernel(
    const float* __restrict__ H, const unsigned short* __restrict__ WpqT,
    unsigned short* __restrict__ P, unsigned short* __restrict__ Q,
    unsigned short* __restrict__ Hbf)
{
  __shared__ unsigned short As[64 * SPQ];
  __shared__ unsigned short Ws[128 * SPQ];

  const int tid  = threadIdx.x;
  const int lane = tid & 63;
  const int wv   = tid >> 6;
  const int lr   = lane & 15;
  const int lq   = lane >> 4;
  const int m0   = wv * 16;
  const int n0   = blockIdx.x * 64;

  for (int i = tid * 8; i < 128 * SPQ; i += 256 * 8)
    *(bf16x8*)&Ws[i] = *(const bf16x8*)&WpqT[i];
  {
    int le = tid >> 2, q = tid & 3;
    int node = n0 + le; if (node >= N_NODES) node = N_NODES - 1;
    const float* src = H + (long)node * 128 + q * 32;
    unsigned short* dst = &As[le * SPQ + q * 32];
    #pragma unroll
    for (int c = 0; c < 32; c += 8) {
      float4 u = *(const float4*)(src + c);
      float4 v = *(const float4*)(src + c + 4);
      *(bf16x8*)(dst + c) = pack8(u, v);
    }
  }
  __syncthreads();

  // export bf16 H tile (coalesced 16B stores from LDS)
  for (int idx = tid * 8; idx < 64 * 128; idx += 256 * 8) {
    int row = idx >> 7, col = idx & 127;
    *(bf16x8*)&Hbf[((long)n0 + row) * 128 + col] = *(const bf16x8*)&As[row * SPQ + col];
  }

  f32x4 zero4 = {0.f, 0.f, 0.f, 0.f};
  f32x4 acc[8];
  #pragma unroll
  for (int f = 0; f < 8; ++f) acc[f] = zero4;
  #pragma unroll
  for (int s = 0; s < 4; ++s) {
    int kb = s * 32 + lq * 8;
    bf16x8 a = *(const bf16x8*)&As[(m0 + lr) * SPQ + kb];
    #pragma unroll
    for (int f = 0; f < 8; ++f) {
      bf16x8 b = *(const bf16x8*)&Ws[(f * 16 + lr) * SPQ + kb];
      acc[f] = __builtin_amdgcn_mfma_f32_16x16x32_bf16(a, b, acc[f], 0, 0, 0);
    }
  }
  #pragma unroll
  for (int f = 0; f < 8; ++f) {
    #pragma unroll
    for (int r = 0; r < 4; ++r) {
      int node = n0 + m0 + lq * 4 + r;
      if (node < N_NODES) {
        if (f < 4) P[(long)node * 64 + f * 16 + lr] = f2bf(acc[f][r]);
        else       Q[(long)node * 64 + (f - 4) * 16 + lr] = f2bf(acc[f][r]);
      }
    }
  }
}

// ---------------------------------------------------------------------------
// edge_compute (R8): segmented-sum aggregation. Each wave owns 13 CONTIGUOUS
// tiles (208 slots); messages land in a wave-private LDS tile [16][MSTR] f32;
// a uniform scalar loop (readlane inode -> SGPR compare) accumulates per-lane
// (lane = channel) and flushes on node change. Interior segments: plain
// coalesced 256B stores. Only chunk-boundary segments (<=2/wave) use atomics.
// Replaces R7's per-edge atomics (2700us, same-address serialization).
// ---------------------------------------------------------------------------
__global__ __launch_bounds__(256, 4) void edge_compute(
    const unsigned short* __restrict__ P, const unsigned short* __restrict__ Q,
    const int* __restrict__ in_s,
    const float4* __restrict__ metaA, const unsigned short* __restrict__ sst,
    const unsigned short* __restrict__ We2T, const float* __restrict__ be2,
    const unsigned short* __restrict__ WrT,
    float* __restrict__ agg)
{
  __shared__ unsigned short W2s[64 * SW2];      // 9.2 KB
  __shared__ unsigned short Es [4 * 16 * SE];   // 9.2 KB
  __shared__ unsigned short At [4 * 16 * ATS];  // 4.0 KB
  __shared__ float          Ms [4 * 16 * MSTR]; // 17.4 KB  (39.9 KB total)

  const int tid  = threadIdx.x;
  const int lane = tid & 63;
  const int wv   = tid >> 6;
  const int lr   = lane & 15;
  const int lq   = lane >> 4;

  for (int i = tid * 8; i < 64 * SW2; i += 256 * 8)
    *(bf16x8*)&W2s[i] = *(const bf16x8*)&We2T[i];

  unsigned short* Es_w = &Es[wv * 16 * SE];
  unsigned short* At_w = &At[wv * 16 * ATS];
  float*          Ms_w = &Ms[wv * 16 * MSTR];

  if (lane < 16) {
    ushort8 z;
    #pragma unroll
    for (int c = 0; c < 8; ++c) z[c] = 0;
    *(ushort8*)&At_w[lane * ATS + 16] = z;
    *(ushort8*)&At_w[lane * ATS + 24] = z;
  }

  bf16x8 aWr[4];
  float bias2[4][4];
  #pragma unroll
  for (int f = 0; f < 4; ++f) {
    aWr[f] = *(const bf16x8*)&WrT[(f * 16 + lr) * 32 + lq * 8];
    #pragma unroll
    for (int r = 0; r < 4; ++r) bias2[f][r] = be2[f * 16 + lq * 4 + r];
  }
  __syncthreads();

  const int n_tiles = N_EDGES / 16;  // 50000
  const int wid = blockIdx.x * 4 + wv;
  const int t0 = wid * EC_CHUNK;
  const int t1 = (t0 + EC_CHUNK < n_tiles) ? (t0 + EC_CHUNK) : n_tiles;
  if (t0 >= n_tiles) return;

  f32x4 zero4 = {0.f, 0.f, 0.f, 0.f};
  int   cur_node   = in_s[t0 * 16];   // uniform broadcast load
  float acc        = 0.f;             // lane = channel accumulator
  bool  use_atomic = true;            // first segment may extend into prev chunk

  for (int tile = t0; tile < t1; ++tile) {
    const int s0 = tile * 16;

    float4 mm = metaA[s0 + lr];
    int   inode = in_s[s0 + lr];
    int   jnode = __float_as_int(mm.w);
    float g     = mm.z;

    if (lane < 16) {
      ushort8 sv = *(const ushort8*)&sst[(long)(s0 + lane) * 8];
      float d2 = mm.x, dl = mm.y;
      unsigned short d2h = f2bf(d2);
      unsigned short d2l = f2bf(d2 - bf2f(d2h));
      unsigned short dlh = f2bf(dl);
      unsigned short dll = f2bf(dl - bf2f(dlh));
      ushort8 w0, w1;
      w0[0] = d2h;   w0[1] = d2l;   w0[2] = dlh;   w0[3] = dll;
      w0[4] = sv[0]; w0[5] = sv[1]; w0[6] = sv[2]; w0[7] = sv[3];
      w1[0] = sv[4]; w1[1] = sv[5]; w1[2] = sv[6]; w1[3] = sv[7];
      w1[4] = 0x3F80u; w1[5] = d2h; w1[6] = dlh;  w1[7] = 0x3F80u;
      *(ushort8*)&At_w[lane * ATS]     = w0;
      *(ushort8*)&At_w[lane * ATS + 8] = w1;
    }

    // R = meta-tail @ Wr (+be1), output: n = f*16+lq*4+r, edge = lr
    bf16x8 bA = *(const bf16x8*)&At_w[lr * ATS + lq * 8];
    f32x4 acc1[4];
    #pragma unroll
    for (int f = 0; f < 4; ++f)
      acc1[f] = __builtin_amdgcn_mfma_f32_16x16x32_bf16(aWr[f], bA, zero4, 0, 0, 0);

    // finish layer 1: e = silu(P[i] + Q[j] + R)
    const unsigned short* Pb = P + (long)inode * 64;
    const unsigned short* Qb = Q + (long)jnode * 64;
    #pragma unroll
    for (int f = 0; f < 4; ++f) {
      short4v pv = *(const short4v*)&Pb[f * 16 + lq * 4];
      short4v qv = *(const short4v*)&Qb[f * 16 + lq * 4];
      float v0 = silu_f(bf2f((unsigned short)pv[0]) + bf2f((unsigned short)qv[0]) + acc1[f][0]);
      float v1 = silu_f(bf2f((unsigned short)pv[1]) + bf2f((unsigned short)qv[1]) + acc1[f][1]);
      float v2 = silu_f(bf2f((unsigned short)pv[2]) + bf2f((unsigned short)qv[2]) + acc1[f][2]);
      float v3 = silu_f(bf2f((unsigned short)pv[3]) + bf2f((unsigned short)qv[3]) + acc1[f][3]);
      uint2 w;
      w.x = cvt_pk_bf16(v0, v1);
      w.y = cvt_pk_bf16(v2, v3);
      *(uint2*)&Es_w[lr * SE + f * 16 + lq * 4] = w;
    }

    // layer 2: acc2[f][r] = (e @ We2)[edge lr][n = f*16+lq*4+r]
    f32x4 acc2[4];
    #pragma unroll
    for (int f = 0; f < 4; ++f) acc2[f] = zero4;
    #pragma unroll
    for (int s = 0; s < 2; ++s) {
      int kb = s * 32 + lq * 8;
      bf16x8 bE = *(const bf16x8*)&Es_w[lr * SE + kb];
      #pragma unroll
      for (int f = 0; f < 4; ++f) {
        bf16x8 aW = *(const bf16x8*)&W2s[(f * 16 + lr) * SW2 + kb];
        acc2[f] = __builtin_amdgcn_mfma_f32_16x16x32_bf16(aW, bE, acc2[f], 0, 0, 0);
      }
    }

    // epilogue: silu+gate -> wave-private msg tile [edge][channel], f32
    #pragma unroll
    for (int f = 0; f < 4; ++f) {
      f32x4 o;
      o[0] = silu_f(acc2[f][0] + bias2[f][0]) * g;
      o[1] = silu_f(acc2[f][1] + bias2[f][1]) * g;
      o[2] = silu_f(acc2[f][2] + bias2[f][2]) * g;
      o[3] = silu_f(acc2[f][3] + bias2[f][3]) * g;
      *(f32x4*)&Ms_w[lr * MSTR + f * 16 + lq * 4] = o;
    }

    // segmented sum over the 16 slot-ordered edges (uniform scalar control)
    #pragma unroll
    for (int e = 0; e < 16; ++e) {
      int ie = __builtin_amdgcn_readlane(inode, e);  // SGPR, uniform
      if (ie != cur_node) {
        if (use_atomic) atomicAdd(&agg[(long)cur_node * 64 + lane], acc);
        else            agg[(long)cur_node * 64 + lane] = acc;
        use_atomic = false;
        cur_node = ie;
        acc = 0.f;
      }
      acc += Ms_w[e * MSTR + lane];
    }
  }
  // final flush: segment may continue into the next chunk
  atomicAdd(&agg[(long)cur_node * 64 + lane], acc);
}

// ---------------------------------------------------------------------------
// node_fused: dense f32 agg read (no CSR walk). phase1 reads bf16 Hbf + agg;
// phase2 upd + residual + LayerNorm. 34 KB LDS -> 4 blocks/CU; h1t rows are
// wave-private (no barrier).
// ---------------------------------------------------------------------------
__global__ __launch_bounds__(256, 4) void node_fused_kernel(
    const float* __restrict__ H, const unsigned short* __restrict__ Hbf,
    const float* __restrict__ agg,
    const unsigned short* __restrict__ Wn1T, const float* __restrict__ bn1,
    const unsigned short* __restrict__ Wn2T, const float* __restrict__ bn2,
    const float* __restrict__ ln_g, const float* __restrict__ ln_b,
    float* __restrict__ out)
{
  __shared__ unsigned short h1t[64 * SH1];  // 33.8 KB

  const int tid  = threadIdx.x;
  const int lane = tid & 63;
  const int wv   = tid >> 6;
  const int lr   = lane & 15;
  const int lq   = lane >> 4;
  const int m0   = wv * 16;
  const int n0   = blockIdx.x * 64;

  // ---- phase 1: h1 tile ----
  int rowa = n0 + m0 + lr;
  int rowc = rowa < N_NODES ? rowa : N_NODES - 1;

  f32x4 zero4 = {0.f, 0.f, 0.f, 0.f};
  f32x4 acc1[16];
  #pragma unroll
  for (int f = 0; f < 16; ++f) acc1[f] = zero4;
  #pragma unroll
  for (int s = 0; s < 6; ++s) {
    int kb = s * 32 + lq * 8;
    bf16x8 a;
    if (s < 4) {
      a = *(const bf16x8*)&Hbf[(long)rowa * 128 + kb];
    } else {
      const float* p = agg + (long)rowc * 64 + (kb - 128);
      float4 u = *(const float4*)p;
      float4 v = *(const float4*)(p + 4);
      a = pack8(u, v);
    }
    #pragma unroll
    for (int f = 0; f < 16; ++f) {
      bf16x8 b = *(const bf16x8*)&Wn1T[(long)(f * 16 + lr) * SN1 + kb];
      acc1[f] = __builtin_amdgcn_mfma_f32_16x16x32_bf16(a, b, acc1[f], 0, 0, 0);
    }
  }
  #pragma unroll
  for (int f = 0; f < 16; ++f) {
    float bias = bn1[f * 16 + lr];
    #pragma unroll
    for (int r = 0; r < 4; ++r)
      h1t[(m0 + lq * 4 + r) * SH1 + f * 16 + lr] = f2bf(silu_f(acc1[f][r] + bias));
  }
  // h1t rows m0..m0+15 are written and read by this wave only: no barrier.

  // ---- phase 2: upd + residual + LayerNorm ----
  f32x4 acc2[8];
  #pragma unroll
  for (int f = 0; f < 8; ++f) acc2[f] = zero4;
  #pragma unroll
  for (int s = 0; s < 8; ++s) {
    int kb = s * 32 + lq * 8;
    bf16x8 a = *(const bf16x8*)&h1t[(m0 + lr) * SH1 + kb];
    #pragma unroll
    for (int f = 0; f < 8; ++f) {
      bf16x8 b = *(const bf16x8*)&Wn2T[(long)(f * 16 + lr) * SN2 + kb];
      acc2[f] = __builtin_amdgcn_mfma_f32_16x16x32_bf16(a, b, acc2[f], 0, 0, 0);
    }
  }

  #pragma unroll
  for (int r = 0; r < 4; ++r) {
    int node = n0 + m0 + lq * 4 + r;
    int nc = node < N_NODES ? node : N_NODES - 1;
    float x[8];
    float sum = 0.f, sumsq = 0.f;
    #pragma unroll
    for (int f = 0; f < 8; ++f) {
      int n = f * 16 + lr;
      float u = acc2[f][r] + bn2[n];
      float xv = H[(long)nc * 128 + n] + u;
      x[f] = xv;
      sum += xv;
      sumsq += xv * xv;
    }
    #pragma unroll
    for (int o = 1; o < 16; o <<= 1) {
      sum   += __shfl_xor(sum, o);
      sumsq += __shfl_xor(sumsq, o);
    }
    float mu  = sum * (1.f / 128.f);
    float var = sumsq * (1.f / 128.f) - mu * mu;
    float rstd = rsqrtf(var + 1e-5f);
    if (node < N_NODES) {
      #pragma unroll
      for (int f = 0; f < 8; ++f) {
        int n = f * 16 + lr;
        out[(long)node * 128 + n] = (x[f] - mu) * rstd * ln_g[n] + ln_b[n];
      }
    }
  }
}

extern "C" void kernel_launch(void* const* d_in, const int* in_sizes, int n_in,
                              void* d_out, int out_size, void* d_ws, size_t ws_size,
                              hipStream_t stream) {
  const float* H       = (const float*)d_in[0];
  const float* xyz     = (const float*)d_in[1];
  const int*   eidx    = (const int*)d_in[2];
  const float* estruct = (const float*)d_in[3];
  const float* erest   = (const float*)d_in[4];
  const float* We1     = (const float*)d_in[5];
  const float* be1     = (const float*)d_in[6];
  const float* We2     = (const float*)d_in[7];
  const float* be2     = (const float*)d_in[8];
  const float* Wg1     = (const float*)d_in[9];
  const float* bg1     = (const float*)d_in[10];
  const float* Wg2     = (const float*)d_in[11];
  const float* bg2     = (const float*)d_in[12];
  const float* Wn1     = (const float*)d_in[13];
  const float* bn1     = (const float*)d_in[14];
  const float* Wn2     = (const float*)d_in[15];
  const float* bn2     = (const float*)d_in[16];
  const float* ln_g    = (const float*)d_in[17];
  const float* ln_b    = (const float*)d_in[18];

  char* ws = (char*)d_ws;
  float*          agg    = (float*)(ws + 0);                    //  12,812,288 (50048*64*4)
  unsigned short* Hbf    = (unsigned short*)(ws + 12812288);    //  12,812,288 (50048*128*2)
  float4*         metaA  = (float4*)(ws + 25624576);            //  12,800,000
  unsigned short* sst    = (unsigned short*)(ws + 38424576);    //  12,800,000
  int*            in_s   = (int*)(ws + 51224576);               //   3,200,000
  int*            order  = (int*)(ws + 54424576);               //   3,200,000 (dead after reorder)
  unsigned short* P      = (unsigned short*)(ws + 54424576);    //   6,400,000 (aliases order)
  unsigned short* Qm     = (unsigned short*)(ws + 60824576);    //   6,400,000
  int*            cnt    = (int*)(ws + 67224576);               //     200,192
  int*            rowptr = (int*)(ws + 67424768);               //     200,192
  int*            cursor = (int*)(ws + 67624960);               //     200,192
  unsigned short* WpqT   = (unsigned short*)(ws + 67825152);    //      34,816
  unsigned short* We2T   = (unsigned short*)(ws + 67859968);    //       9,216
  unsigned short* Wn1T   = (unsigned short*)(ws + 67869184);    //     102,400
  unsigned short* Wn2T   = (unsigned short*)(ws + 67971584);    //      67,584
  unsigned short* WrT    = (unsigned short*)(ws + 68039168);    //       4,096
  float* out = (float*)d_out;

  hipMemsetAsync(cnt, 0, (size_t)N_NODES * sizeof(int), stream);
  hipMemsetAsync(agg, 0, (size_t)50048 * 64 * sizeof(float), stream);

  hipLaunchKernelGGL(prep_hist, dim3(3125), dim3(256), 0, stream,
                     eidx, We1, be1, We2, Wn1, Wn2, WpqT, We2T, Wn1T, Wn2T, WrT, cnt);
  hipLaunchKernelGGL(scan_kernel, dim3(1), dim3(1024), 0, stream,
                     cnt, rowptr, cursor);
  hipLaunchKernelGGL(fill_kernel, dim3(3125), dim3(256), 0, stream,
                     eidx, cursor, order);
  hipLaunchKernelGGL(reorder_kernel, dim3(3125), dim3(256), 0, stream,
                     eidx, xyz, estruct, erest, order,
                     Wg1, bg1, Wg2, bg2, metaA, sst, in_s);
  hipLaunchKernelGGL(pq_kernel, dim3(NODE_TILES), dim3(256), 0, stream,
                     H, WpqT, P, Qm, Hbf);
  hipLaunchKernelGGL(edge_compute, dim3(EC_GRID), dim3(256), 0, stream,
                     P, Qm, in_s, metaA, sst, We2T, be2, WrT, agg);
  hipLaunchKernelGGL(node_fused_kernel, dim3(NODE_TILES), dim3(256), 0, stream,
                     H, Hbf, agg, Wn1T, bn1, Wn2T, bn2, ln_g, ln_b, out);
}

// Round 4
// 402.036 us; speedup vs baseline: 7.5944x; 1.1742x over previous
//
#include <hip/hip_runtime.h>
#include <stdint.h>

#define N_NODES 50000
#define N_EDGES 800000
#define NODE_TILES 782              // ceil(50000/64)

#define SE   72    // e-tile stride (bf16)
#define SW2  72
#define SPQ  136   // pq kernel strides (K=128)
#define SN1  200   // Wn1T row stride (K=192)
#define SN2  264   // Wn2T row stride (K=256)
#define SH1  264   // h1 LDS tile stride
#define ATS  32    // edge A-tile row stride (K=32, k>=16 zero)
#define MSTR 68    // msg LDS row stride in f32 (64 + 4 pad)

#define EC_GRID 962   // 962*4 waves * 13 tiles = 50024 >= 50000
#define EC_CHUNK 13

#define SCAN_B 98     // 98*512 = 50176 >= 50000

typedef short bf16x8 __attribute__((ext_vector_type(8)));
typedef short short4v __attribute__((ext_vector_type(4)));
typedef unsigned short ushort8 __attribute__((ext_vector_type(8)));
typedef float f32x4  __attribute__((ext_vector_type(4)));

static __device__ __forceinline__ unsigned short f2bf(float f) {
  unsigned int x = __float_as_uint(f);
  unsigned int r = (x + 0x7fffu + ((x >> 16) & 1u)) >> 16;
  return (unsigned short)r;
}
static __device__ __forceinline__ float bf2f(unsigned short u) {
  return __uint_as_float(((unsigned int)u) << 16);
}
// silu via v_rcp_f32: avoids the full-precision fdiv expansion
static __device__ __forceinline__ float silu_f(float x) {
  return x * __builtin_amdgcn_rcpf(1.0f + __expf(-x));
}
static __device__ __forceinline__ float sigmoid_f(float x) {
  return __builtin_amdgcn_rcpf(1.0f + __expf(-x));
}
static __device__ __forceinline__ unsigned int cvt_pk_bf16(float lo, float hi) {
  unsigned int r;
  asm("v_cvt_pk_bf16_f32 %0, %1, %2" : "=v"(r) : "v"(lo), "v"(hi));
  return r;
}
static __device__ __forceinline__ bf16x8 pack8(float4 u, float4 v) {
  bf16x8 w;
  w[0] = (short)f2bf(u.x); w[1] = (short)f2bf(u.y);
  w[2] = (short)f2bf(u.z); w[3] = (short)f2bf(u.w);
  w[4] = (short)f2bf(v.x); w[5] = (short)f2bf(v.y);
  w[6] = (short)f2bf(v.z); w[7] = (short)f2bf(v.w);
  return w;
}

// ---------------------------------------------------------------------------
// prep: natural transposed bf16 weights + destination histogram.
// WrT: 64 x 32 bf16 B-operand for the rank-10+bias tail of layer 1.
// ---------------------------------------------------------------------------
__global__ void prep_hist(
    const int* __restrict__ eidx,
    const float* __restrict__ We1, const float* __restrict__ be1,
    const float* __restrict__ We2,
    const float* __restrict__ Wn1, const float* __restrict__ Wn2,
    unsigned short* __restrict__ WpqT, unsigned short* __restrict__ We2T,
    unsigned short* __restrict__ Wn1T, unsigned short* __restrict__ Wn2T,
    unsigned short* __restrict__ WrT,
    int* __restrict__ cnt)
{
  const int gid = blockIdx.x * 256 + threadIdx.x;
  const int gsz = gridDim.x * 256;
  for (int i = gid; i < 128 * SPQ; i += gsz) {
    int n = i / SPQ, k = i % SPQ;
    unsigned short v = 0;
    if (k < 128) v = (n < 64) ? f2bf(We1[k * 64 + n]) : f2bf(We1[(128 + k) * 64 + (n - 64)]);
    WpqT[i] = v;
  }
  for (int i = gid; i < 64 * SW2; i += gsz) {
    int n = i / SW2, k = i % SW2;
    We2T[i] = (k < 64) ? f2bf(We2[k * 64 + n]) : (unsigned short)0;
  }
  for (int i = gid; i < 256 * SN1; i += gsz) {
    int n = i / SN1, k = i % SN1;
    Wn1T[i] = (k < 192) ? f2bf(Wn1[k * 256 + n]) : (unsigned short)0;
  }
  for (int i = gid; i < 128 * SN2; i += gsz) {
    int n = i / SN2, k = i % SN2;
    Wn2T[i] = (k < 256) ? f2bf(Wn2[k * 128 + n]) : (unsigned short)0;
  }
  for (int i = gid; i < 64 * 32; i += gsz) {
    int n = i >> 5, k = i & 31;
    float v = 0.f;
    if (k < 2)       v = We1[256 * 64 + n];
    else if (k < 4)  v = We1[257 * 64 + n];
    else if (k < 12) v = We1[(258 + (k - 4)) * 64 + n];
    else if (k == 12) v = be1[n];
    else if (k == 13) { float w = We1[256 * 64 + n]; v = w - bf2f(f2bf(w)); }
    else if (k == 14) { float w = We1[257 * 64 + n]; v = w - bf2f(f2bf(w)); }
    else if (k == 15) { float w = be1[n];            v = w - bf2f(f2bf(w)); }
    WrT[i] = (k < 16) ? f2bf(v) : (unsigned short)0;
  }
  if (gid < N_EDGES) atomicAdd(&cnt[eidx[gid]], 1);
}

// ---------------------------------------------------------------------------
// scan, hierarchical (R9): replaces the single-block 81us scan.
// local: per-block exclusive prefix (coalesced, no per-thread arrays);
// mid: scan the 98 block sums; add: cursor = local + block offset.
// ---------------------------------------------------------------------------
__global__ __launch_bounds__(512) void scan_local(
    const int* __restrict__ cnt, int* __restrict__ rowptr,
    int* __restrict__ bsum)
{
  __shared__ int wsum[8], woff[8];
  const int t = threadIdx.x;
  const int idx = blockIdx.x * 512 + t;
  const int lane = t & 63, wid = t >> 6;
  int c = (idx < N_NODES) ? cnt[idx] : 0;
  int v = c;
  #pragma unroll
  for (int o = 1; o < 64; o <<= 1) {
    int u = __shfl_up(v, o);
    if (lane >= o) v += u;
  }
  if (lane == 63) wsum[wid] = v;
  __syncthreads();
  if (t == 0) {
    int a = 0;
    #pragma unroll
    for (int w = 0; w < 8; ++w) { woff[w] = a; a += wsum[w]; }
    bsum[blockIdx.x] = a;
  }
  __syncthreads();
  if (idx < N_NODES) rowptr[idx] = woff[wid] + (v - c);  // local exclusive
}

__global__ __launch_bounds__(128) void scan_mid(
    const int* __restrict__ bsum, int* __restrict__ boff)
{
  __shared__ int ws[2];
  const int t = threadIdx.x;
  const int lane = t & 63, wid = t >> 6;
  int c = (t < SCAN_B) ? bsum[t] : 0;
  int v = c;
  #pragma unroll
  for (int o = 1; o < 64; o <<= 1) {
    int u = __shfl_up(v, o);
    if (lane >= o) v += u;
  }
  if (lane == 63) ws[wid] = v;
  __syncthreads();
  int add = (wid == 1) ? ws[0] : 0;
  if (t < SCAN_B) boff[t] = add + (v - c);
}

__global__ __launch_bounds__(512) void scan_add(
    const int* __restrict__ rowptr, const int* __restrict__ boff,
    int* __restrict__ cursor)
{
  const int idx = blockIdx.x * 512 + threadIdx.x;
  if (idx < N_NODES) cursor[idx] = rowptr[idx] + boff[blockIdx.x];
}

// ---------------------------------------------------------------------------
// fill: order[slot] = edge id (4-B scatter only).
// ---------------------------------------------------------------------------
__global__ void fill_kernel(const int* __restrict__ eidx,
                            int* __restrict__ cursor, int* __restrict__ order)
{
  int e = blockIdx.x * 256 + threadIdx.x;
  if (e < N_EDGES) {
    int d = eidx[e];
    int pos = atomicAdd(&cursor[d], 1);
    order[pos] = e;
  }
}

// ---------------------------------------------------------------------------
// reorder: one thread per CSR slot. Gathers per-edge metadata into slot order;
// computes d2/delta + gate MLP here.
// ---------------------------------------------------------------------------
__global__ void reorder_kernel(
    const int* __restrict__ eidx, const float* __restrict__ xyz,
    const float* __restrict__ estruct, const float* __restrict__ erest,
    const int* __restrict__ order,
    const float* __restrict__ Wg1, const float* __restrict__ bg1,
    const float* __restrict__ Wg2, const float* __restrict__ bg2,
    float4* __restrict__ metaA, unsigned short* __restrict__ sst,
    int* __restrict__ in_s)
{
  int s = blockIdx.x * 256 + threadIdx.x;
  if (s >= N_EDGES) return;
  int e = order[s];
  int i = eidx[e], j = eidx[N_EDGES + e];
  float dx = xyz[i * 3 + 0] - xyz[j * 3 + 0];
  float dy = xyz[i * 3 + 1] - xyz[j * 3 + 1];
  float dz = xyz[i * 3 + 2] - xyz[j * 3 + 2];
  float d2 = dx * dx + dy * dy + dz * dz;
  float dist = sqrtf(d2 + 1e-9f);
  float rest = erest[e];
  float dl = (dist - rest) / (rest + 1e-9f);
  float4 s0 = *(const float4*)&estruct[e * 8];
  float4 s1 = *(const float4*)&estruct[e * 8 + 4];
  float st[8] = {s0.x, s0.y, s0.z, s0.w, s1.x, s1.y, s1.z, s1.w};
  float gsum = 0.f;
  #pragma unroll
  for (int h = 0; h < 32; ++h) {
    float a = bg1[h] + d2 * Wg1[0 * 32 + h] + dl * Wg1[1 * 32 + h];
    #pragma unroll
    for (int c = 0; c < 8; ++c) a += st[c] * Wg1[(2 + c) * 32 + h];
    gsum += silu_f(a) * Wg2[h];
  }
  float g = sigmoid_f(gsum + bg2[0]);
  metaA[s] = make_float4(d2, dl, g, __int_as_float(j));
  ushort8 w;
  #pragma unroll
  for (int c = 0; c < 8; ++c) w[c] = f2bf(st[c]);
  *(ushort8*)&sst[(long)s * 8] = w;
  in_s[s] = i;
}

// ---------------------------------------------------------------------------
// pq: [P|Q] = H @ [We1[0:128] | We1[128:256]], bf16, natural layout.
// Also exports the bf16-converted H tile to Hbf (reused by node_fused).
// ---------------------------------------------------------------------------
__global__ __launch_bounds__(256, 2) void pq_kernel(
    const float* __restrict__ H, const unsigned short* __restrict__ WpqT,
    unsigned short* __restrict__ P, unsigned short* __restrict__ Q,
    unsigned short* __restrict__ Hbf)
{
  __shared__ unsigned short As[64 * SPQ];
  __shared__ unsigned short Ws[128 * SPQ];

  const int tid  = threadIdx.x;
  const int lane = tid & 63;
  const int wv   = tid >> 6;
  const int lr   = lane & 15;
  const int lq   = lane >> 4;
  const int m0   = wv * 16;
  const int n0   = blockIdx.x * 64;

  for (int i = tid * 8; i < 128 * SPQ; i += 256 * 8)
    *(bf16x8*)&Ws[i] = *(const bf16x8*)&WpqT[i];
  {
    int le = tid >> 2, q = tid & 3;
    int node = n0 + le; if (node >= N_NODES) node = N_NODES - 1;
    const float* src = H + (long)node * 128 + q * 32;
    unsigned short* dst = &As[le * SPQ + q * 32];
    #pragma unroll
    for (int c = 0; c < 32; c += 8) {
      float4 u = *(const float4*)(src + c);
      float4 v = *(const float4*)(src + c + 4);
      *(bf16x8*)(dst + c) = pack8(u, v);
    }
  }
  __syncthreads();

  // export bf16 H tile (coalesced 16B stores from LDS)
  for (int idx = tid * 8; idx < 64 * 128; idx += 256 * 8) {
    int row = idx >> 7, col = idx & 127;
    *(bf16x8*)&Hbf[((long)n0 + row) * 128 + col] = *(const bf16x8*)&As[row * SPQ + col];
  }

  f32x4 zero4 = {0.f, 0.f, 0.f, 0.f};
  f32x4 acc[8];
  #pragma unroll
  for (int f = 0; f < 8; ++f) acc[f] = zero4;
  #pragma unroll
  for (int s = 0; s < 4; ++s) {
    int kb = s * 32 + lq * 8;
    bf16x8 a = *(const bf16x8*)&As[(m0 + lr) * SPQ + kb];
    #pragma unroll
    for (int f = 0; f < 8; ++f) {
      bf16x8 b = *(const bf16x8*)&Ws[(f * 16 + lr) * SPQ + kb];
      acc[f] = __builtin_amdgcn_mfma_f32_16x16x32_bf16(a, b, acc[f], 0, 0, 0);
    }
  }
  #pragma unroll
  for (int f = 0; f < 8; ++f) {
    #pragma unroll
    for (int r = 0; r < 4; ++r) {
      int node = n0 + m0 + lq * 4 + r;
      if (node < N_NODES) {
        if (f < 4) P[(long)node * 64 + f * 16 + lr] = f2bf(acc[f][r]);
        else       Q[(long)node * 64 + (f - 4) * 16 + lr] = f2bf(acc[f][r]);
      }
    }
  }
}

// ---------------------------------------------------------------------------
// edge_compute (R8): segmented-sum aggregation. Each wave owns 13 CONTIGUOUS
// tiles; messages land in a wave-private LDS tile [16][MSTR] f32; a uniform
// scalar loop (readlane inode -> SGPR compare) accumulates per-lane
// (lane = channel) and flushes on node change. Interior segments: plain
// coalesced 256B stores. Only chunk-boundary segments use atomics.
// ---------------------------------------------------------------------------
__global__ __launch_bounds__(256, 4) void edge_compute(
    const unsigned short* __restrict__ P, const unsigned short* __restrict__ Q,
    const int* __restrict__ in_s,
    const float4* __restrict__ metaA, const unsigned short* __restrict__ sst,
    const unsigned short* __restrict__ We2T, const float* __restrict__ be2,
    const unsigned short* __restrict__ WrT,
    float* __restrict__ agg)
{
  __shared__ unsigned short W2s[64 * SW2];      // 9.2 KB
  __shared__ unsigned short Es [4 * 16 * SE];   // 9.2 KB
  __shared__ unsigned short At [4 * 16 * ATS];  // 4.0 KB
  __shared__ float          Ms [4 * 16 * MSTR]; // 17.4 KB  (39.9 KB total)

  const int tid  = threadIdx.x;
  const int lane = tid & 63;
  const int wv   = tid >> 6;
  const int lr   = lane & 15;
  const int lq   = lane >> 4;

  for (int i = tid * 8; i < 64 * SW2; i += 256 * 8)
    *(bf16x8*)&W2s[i] = *(const bf16x8*)&We2T[i];

  unsigned short* Es_w = &Es[wv * 16 * SE];
  unsigned short* At_w = &At[wv * 16 * ATS];
  float*          Ms_w = &Ms[wv * 16 * MSTR];

  if (lane < 16) {
    ushort8 z;
    #pragma unroll
    for (int c = 0; c < 8; ++c) z[c] = 0;
    *(ushort8*)&At_w[lane * ATS + 16] = z;
    *(ushort8*)&At_w[lane * ATS + 24] = z;
  }

  bf16x8 aWr[4];
  float bias2[4][4];
  #pragma unroll
  for (int f = 0; f < 4; ++f) {
    aWr[f] = *(const bf16x8*)&WrT[(f * 16 + lr) * 32 + lq * 8];
    #pragma unroll
    for (int r = 0; r < 4; ++r) bias2[f][r] = be2[f * 16 + lq * 4 + r];
  }
  __syncthreads();

  const int n_tiles = N_EDGES / 16;  // 50000
  const int wid = blockIdx.x * 4 + wv;
  const int t0 = wid * EC_CHUNK;
  const int t1 = (t0 + EC_CHUNK < n_tiles) ? (t0 + EC_CHUNK) : n_tiles;
  if (t0 >= n_tiles) return;

  f32x4 zero4 = {0.f, 0.f, 0.f, 0.f};
  int   cur_node   = in_s[t0 * 16];   // uniform broadcast load
  float acc        = 0.f;             // lane = channel accumulator
  bool  use_atomic = true;            // first segment may extend into prev chunk

  for (int tile = t0; tile < t1; ++tile) {
    const int s0 = tile * 16;

    float4 mm = metaA[s0 + lr];
    int   inode = in_s[s0 + lr];
    int   jnode = __float_as_int(mm.w);
    float g     = mm.z;

    if (lane < 16) {
      ushort8 sv = *(const ushort8*)&sst[(long)(s0 + lane) * 8];
      float d2 = mm.x, dl = mm.y;
      unsigned short d2h = f2bf(d2);
      unsigned short d2l = f2bf(d2 - bf2f(d2h));
      unsigned short dlh = f2bf(dl);
      unsigned short dll = f2bf(dl - bf2f(dlh));
      ushort8 w0, w1;
      w0[0] = d2h;   w0[1] = d2l;   w0[2] = dlh;   w0[3] = dll;
      w0[4] = sv[0]; w0[5] = sv[1]; w0[6] = sv[2]; w0[7] = sv[3];
      w1[0] = sv[4]; w1[1] = sv[5]; w1[2] = sv[6]; w1[3] = sv[7];
      w1[4] = 0x3F80u; w1[5] = d2h; w1[6] = dlh;  w1[7] = 0x3F80u;
      *(ushort8*)&At_w[lane * ATS]     = w0;
      *(ushort8*)&At_w[lane * ATS + 8] = w1;
    }

    // R = meta-tail @ Wr (+be1), output: n = f*16+lq*4+r, edge = lr
    bf16x8 bA = *(const bf16x8*)&At_w[lr * ATS + lq * 8];
    f32x4 acc1[4];
    #pragma unroll
    for (int f = 0; f < 4; ++f)
      acc1[f] = __builtin_amdgcn_mfma_f32_16x16x32_bf16(aWr[f], bA, zero4, 0, 0, 0);

    // finish layer 1: e = silu(P[i] + Q[j] + R)
    const unsigned short* Pb = P + (long)inode * 64;
    const unsigned short* Qb = Q + (long)jnode * 64;
    #pragma unroll
    for (int f = 0; f < 4; ++f) {
      short4v pv = *(const short4v*)&Pb[f * 16 + lq * 4];
      short4v qv = *(const short4v*)&Qb[f * 16 + lq * 4];
      float v0 = silu_f(bf2f((unsigned short)pv[0]) + bf2f((unsigned short)qv[0]) + acc1[f][0]);
      float v1 = silu_f(bf2f((unsigned short)pv[1]) + bf2f((unsigned short)qv[1]) + acc1[f][1]);
      float v2 = silu_f(bf2f((unsigned short)pv[2]) + bf2f((unsigned short)qv[2]) + acc1[f][2]);
      float v3 = silu_f(bf2f((unsigned short)pv[3]) + bf2f((unsigned short)qv[3]) + acc1[f][3]);
      uint2 w;
      w.x = cvt_pk_bf16(v0, v1);
      w.y = cvt_pk_bf16(v2, v3);
      *(uint2*)&Es_w[lr * SE + f * 16 + lq * 4] = w;
    }

    // layer 2: acc2[f][r] = (e @ We2)[edge lr][n = f*16+lq*4+r]
    f32x4 acc2[4];
    #pragma unroll
    for (int f = 0; f < 4; ++f) acc2[f] = zero4;
    #pragma unroll
    for (int s = 0; s < 2; ++s) {
      int kb = s * 32 + lq * 8;
      bf16x8 bE = *(const bf16x8*)&Es_w[lr * SE + kb];
      #pragma unroll
      for (int f = 0; f < 4; ++f) {
        bf16x8 aW = *(const bf16x8*)&W2s[(f * 16 + lr) * SW2 + kb];
        acc2[f] = __builtin_amdgcn_mfma_f32_16x16x32_bf16(aW, bE, acc2[f], 0, 0, 0);
      }
    }

    // epilogue: silu+gate -> wave-private msg tile [edge][channel], f32
    #pragma unroll
    for (int f = 0; f < 4; ++f) {
      f32x4 o;
      o[0] = silu_f(acc2[f][0] + bias2[f][0]) * g;
      o[1] = silu_f(acc2[f][1] + bias2[f][1]) * g;
      o[2] = silu_f(acc2[f][2] + bias2[f][2]) * g;
      o[3] = silu_f(acc2[f][3] + bias2[f][3]) * g;
      *(f32x4*)&Ms_w[lr * MSTR + f * 16 + lq * 4] = o;
    }

    // segmented sum over the 16 slot-ordered edges (uniform scalar control)
    #pragma unroll
    for (int e = 0; e < 16; ++e) {
      int ie = __builtin_amdgcn_readlane(inode, e);  // SGPR, uniform
      if (ie != cur_node) {
        if (use_atomic) atomicAdd(&agg[(long)cur_node * 64 + lane], acc);
        else            agg[(long)cur_node * 64 + lane] = acc;
        use_atomic = false;
        cur_node = ie;
        acc = 0.f;
      }
      acc += Ms_w[e * MSTR + lane];
    }
  }
  // final flush: segment may continue into the next chunk
  atomicAdd(&agg[(long)cur_node * 64 + lane], acc);
}

// ---------------------------------------------------------------------------
// node_fused: dense f32 agg read (no CSR walk). phase1 reads bf16 Hbf + agg;
// phase2 upd + residual + LayerNorm. 34 KB LDS -> 4 blocks/CU; h1t rows are
// wave-private (no barrier).
// ---------------------------------------------------------------------------
__global__ __launch_bounds__(256, 4) void node_fused_kernel(
    const float* __restrict__ H, const unsigned short* __restrict__ Hbf,
    const float* __restrict__ agg,
    const unsigned short* __restrict__ Wn1T, const float* __restrict__ bn1,
    const unsigned short* __restrict__ Wn2T, const float* __restrict__ bn2,
    const float* __restrict__ ln_g, const float* __restrict__ ln_b,
    float* __restrict__ out)
{
  __shared__ unsigned short h1t[64 * SH1];  // 33.8 KB

  const int tid  = threadIdx.x;
  const int lane = tid & 63;
  const int wv   = tid >> 6;
  const int lr   = lane & 15;
  const int lq   = lane >> 4;
  const int m0   = wv * 16;
  const int n0   = blockIdx.x * 64;

  // ---- phase 1: h1 tile ----
  int rowa = n0 + m0 + lr;
  int rowc = rowa < N_NODES ? rowa : N_NODES - 1;

  f32x4 zero4 = {0.f, 0.f, 0.f, 0.f};
  f32x4 acc1[16];
  #pragma unroll
  for (int f = 0; f < 16; ++f) acc1[f] = zero4;
  #pragma unroll
  for (int s = 0; s < 6; ++s) {
    int kb = s * 32 + lq * 8;
    bf16x8 a;
    if (s < 4) {
      a = *(const bf16x8*)&Hbf[(long)rowa * 128 + kb];
    } else {
      const float* p = agg + (long)rowc * 64 + (kb - 128);
      float4 u = *(const float4*)p;
      float4 v = *(const float4*)(p + 4);
      a = pack8(u, v);
    }
    #pragma unroll
    for (int f = 0; f < 16; ++f) {
      bf16x8 b = *(const bf16x8*)&Wn1T[(long)(f * 16 + lr) * SN1 + kb];
      acc1[f] = __builtin_amdgcn_mfma_f32_16x16x32_bf16(a, b, acc1[f], 0, 0, 0);
    }
  }
  #pragma unroll
  for (int f = 0; f < 16; ++f) {
    float bias = bn1[f * 16 + lr];
    #pragma unroll
    for (int r = 0; r < 4; ++r)
      h1t[(m0 + lq * 4 + r) * SH1 + f * 16 + lr] = f2bf(silu_f(acc1[f][r] + bias));
  }
  // h1t rows m0..m0+15 are written and read by this wave only: no barrier.

  // ---- phase 2: upd + residual + LayerNorm ----
  f32x4 acc2[8];
  #pragma unroll
  for (int f = 0; f < 8; ++f) acc2[f] = zero4;
  #pragma unroll
  for (int s = 0; s < 8; ++s) {
    int kb = s * 32 + lq * 8;
    bf16x8 a = *(const bf16x8*)&h1t[(m0 + lr) * SH1 + kb];
    #pragma unroll
    for (int f = 0; f < 8; ++f) {
      bf16x8 b = *(const bf16x8*)&Wn2T[(long)(f * 16 + lr) * SN2 + kb];
      acc2[f] = __builtin_amdgcn_mfma_f32_16x16x32_bf16(a, b, acc2[f], 0, 0, 0);
    }
  }

  #pragma unroll
  for (int r = 0; r < 4; ++r) {
    int node = n0 + m0 + lq * 4 + r;
    int nc = node < N_NODES ? node : N_NODES - 1;
    float x[8];
    float sum = 0.f, sumsq = 0.f;
    #pragma unroll
    for (int f = 0; f < 8; ++f) {
      int n = f * 16 + lr;
      float u = acc2[f][r] + bn2[n];
      float xv = H[(long)nc * 128 + n] + u;
      x[f] = xv;
      sum += xv;
      sumsq += xv * xv;
    }
    #pragma unroll
    for (int o = 1; o < 16; o <<= 1) {
      sum   += __shfl_xor(sum, o);
      sumsq += __shfl_xor(sumsq, o);
    }
    float mu  = sum * (1.f / 128.f);
    float var = sumsq * (1.f / 128.f) - mu * mu;
    float rstd = rsqrtf(var + 1e-5f);
    if (node < N_NODES) {
      #pragma unroll
      for (int f = 0; f < 8; ++f) {
        int n = f * 16 + lr;
        out[(long)node * 128 + n] = (x[f] - mu) * rstd * ln_g[n] + ln_b[n];
      }
    }
  }
}

extern "C" void kernel_launch(void* const* d_in, const int* in_sizes, int n_in,
                              void* d_out, int out_size, void* d_ws, size_t ws_size,
                              hipStream_t stream) {
  const float* H       = (const float*)d_in[0];
  const float* xyz     = (const float*)d_in[1];
  const int*   eidx    = (const int*)d_in[2];
  const float* estruct = (const float*)d_in[3];
  const float* erest   = (const float*)d_in[4];
  const float* We1     = (const float*)d_in[5];
  const float* be1     = (const float*)d_in[6];
  const float* We2     = (const float*)d_in[7];
  const float* be2     = (const float*)d_in[8];
  const float* Wg1     = (const float*)d_in[9];
  const float* bg1     = (const float*)d_in[10];
  const float* Wg2     = (const float*)d_in[11];
  const float* bg2     = (const float*)d_in[12];
  const float* Wn1     = (const float*)d_in[13];
  const float* bn1     = (const float*)d_in[14];
  const float* Wn2     = (const float*)d_in[15];
  const float* bn2     = (const float*)d_in[16];
  const float* ln_g    = (const float*)d_in[17];
  const float* ln_b    = (const float*)d_in[18];

  char* ws = (char*)d_ws;
  float*          agg    = (float*)(ws + 0);                    //  12,812,288 (50048*64*4)
  unsigned short* Hbf    = (unsigned short*)(ws + 12812288);    //  12,812,288 (50048*128*2)
  float4*         metaA  = (float4*)(ws + 25624576);            //  12,800,000
  unsigned short* sst    = (unsigned short*)(ws + 38424576);    //  12,800,000
  int*            in_s   = (int*)(ws + 51224576);               //   3,200,000
  int*            order  = (int*)(ws + 54424576);               //   3,200,000 (dead after reorder)
  unsigned short* P      = (unsigned short*)(ws + 54424576);    //   6,400,000 (aliases order)
  unsigned short* Qm     = (unsigned short*)(ws + 60824576);    //   6,400,000
  int*            cnt    = (int*)(ws + 67224576);               //     200,192
  int*            rowptr = (int*)(ws + 67424768);               //     200,192 (scan temp)
  int*            cursor = (int*)(ws + 67624960);               //     200,192
  unsigned short* WpqT   = (unsigned short*)(ws + 67825152);    //      34,816
  unsigned short* We2T   = (unsigned short*)(ws + 67859968);    //       9,216
  unsigned short* Wn1T   = (unsigned short*)(ws + 67869184);    //     102,400
  unsigned short* Wn2T   = (unsigned short*)(ws + 67971584);    //      67,584
  unsigned short* WrT    = (unsigned short*)(ws + 68039168);    //       4,096
  int*            bsum   = (int*)(ws + 68043264);               //         512
  int*            boff   = (int*)(ws + 68043776);               //         512
  float* out = (float*)d_out;

  hipMemsetAsync(cnt, 0, (size_t)N_NODES * sizeof(int), stream);
  hipMemsetAsync(agg, 0, (size_t)50048 * 64 * sizeof(float), stream);

  hipLaunchKernelGGL(prep_hist, dim3(3125), dim3(256), 0, stream,
                     eidx, We1, be1, We2, Wn1, Wn2, WpqT, We2T, Wn1T, Wn2T, WrT, cnt);
  hipLaunchKernelGGL(scan_local, dim3(SCAN_B), dim3(512), 0, stream,
                     cnt, rowptr, bsum);
  hipLaunchKernelGGL(scan_mid, dim3(1), dim3(128), 0, stream,
                     bsum, boff);
  hipLaunchKernelGGL(scan_add, dim3(SCAN_B), dim3(512), 0, stream,
                     rowptr, boff, cursor);
  hipLaunchKernelGGL(fill_kernel, dim3(3125), dim3(256), 0, stream,
                     eidx, cursor, order);
  hipLaunchKernelGGL(reorder_kernel, dim3(3125), dim3(256), 0, stream,
                     eidx, xyz, estruct, erest, order,
                     Wg1, bg1, Wg2, bg2, metaA, sst, in_s);
  hipLaunchKernelGGL(pq_kernel, dim3(NODE_TILES), dim3(256), 0, stream,
                     H, WpqT, P, Qm, Hbf);
  hipLaunchKernelGGL(edge_compute, dim3(EC_GRID), dim3(256), 0, stream,
                     P, Qm, in_s, metaA, sst, We2T, be2, WrT, agg);
  hipLaunchKernelGGL(node_fused_kernel, dim3(NODE_TILES), dim3(256), 0, stream,
                     H, Hbf, agg, Wn1T, bn1, Wn2T, bn2, ln_g, ln_b, out);
}

// Round 5
// 389.721 us; speedup vs baseline: 7.8343x; 1.0316x over previous
//
#include <hip/hip_runtime.h>
#include <stdint.h>

#define N_NODES 50000
#define N_EDGES 800000
#define NODE_TILES 782              // ceil(50000/64)

#define SE   72    // e-tile stride (bf16)
#define SW2  72
#define SPQ  136   // pq kernel strides (K=128)
#define SN1  216   // Wn1T row stride (K=192) -- dword 108 == 12 mod 32: 2-way
#define SN2  280   // Wn2T row stride (K=256) -- dword 140 == 12 mod 32: 2-way
#define ATS  40    // edge A-tile row stride (dword 20: 2-way, 16B-aligned)
#define MSTR 72    // msg LDS row stride (bf16)

#define EC_GRID 962   // 962*4 waves * 13 tiles = 50024 >= 50000
#define EC_CHUNK 13

#define SCAN_B 98     // 98*512 = 50176 >= 50000

typedef short bf16x8 __attribute__((ext_vector_type(8)));
typedef short short4v __attribute__((ext_vector_type(4)));
typedef unsigned short ushort8 __attribute__((ext_vector_type(8)));
typedef float f32x4  __attribute__((ext_vector_type(4)));

static __device__ __forceinline__ unsigned short f2bf(float f) {
  unsigned int x = __float_as_uint(f);
  unsigned int r = (x + 0x7fffu + ((x >> 16) & 1u)) >> 16;
  return (unsigned short)r;
}
static __device__ __forceinline__ float bf2f(unsigned short u) {
  return __uint_as_float(((unsigned int)u) << 16);
}
static __device__ __forceinline__ float silu_f(float x) {
  return x * __builtin_amdgcn_rcpf(1.0f + __expf(-x));
}
static __device__ __forceinline__ float sigmoid_f(float x) {
  return __builtin_amdgcn_rcpf(1.0f + __expf(-x));
}
static __device__ __forceinline__ unsigned int cvt_pk_bf16(float lo, float hi) {
  unsigned int r;
  asm("v_cvt_pk_bf16_f32 %0, %1, %2" : "=v"(r) : "v"(lo), "v"(hi));
  return r;
}
static __device__ __forceinline__ bf16x8 pack8(float4 u, float4 v) {
  bf16x8 w;
  w[0] = (short)f2bf(u.x); w[1] = (short)f2bf(u.y);
  w[2] = (short)f2bf(u.z); w[3] = (short)f2bf(u.w);
  w[4] = (short)f2bf(v.x); w[5] = (short)f2bf(v.y);
  w[6] = (short)f2bf(v.z); w[7] = (short)f2bf(v.w);
  return w;
}

// ---------------------------------------------------------------------------
// prep: natural transposed bf16 weights + destination histogram.
// ---------------------------------------------------------------------------
__global__ void prep_hist(
    const int* __restrict__ eidx,
    const float* __restrict__ We1, const float* __restrict__ be1,
    const float* __restrict__ We2,
    const float* __restrict__ Wn1, const float* __restrict__ Wn2,
    unsigned short* __restrict__ WpqT, unsigned short* __restrict__ We2T,
    unsigned short* __restrict__ Wn1T, unsigned short* __restrict__ Wn2T,
    unsigned short* __restrict__ WrT,
    int* __restrict__ cnt)
{
  const int gid = blockIdx.x * 256 + threadIdx.x;
  const int gsz = gridDim.x * 256;
  for (int i = gid; i < 128 * SPQ; i += gsz) {
    int n = i / SPQ, k = i % SPQ;
    unsigned short v = 0;
    if (k < 128) v = (n < 64) ? f2bf(We1[k * 64 + n]) : f2bf(We1[(128 + k) * 64 + (n - 64)]);
    WpqT[i] = v;
  }
  for (int i = gid; i < 64 * SW2; i += gsz) {
    int n = i / SW2, k = i % SW2;
    We2T[i] = (k < 64) ? f2bf(We2[k * 64 + n]) : (unsigned short)0;
  }
  for (int i = gid; i < 256 * SN1; i += gsz) {
    int n = i / SN1, k = i % SN1;
    Wn1T[i] = (k < 192) ? f2bf(Wn1[k * 256 + n]) : (unsigned short)0;
  }
  for (int i = gid; i < 128 * SN2; i += gsz) {
    int n = i / SN2, k = i % SN2;
    Wn2T[i] = (k < 256) ? f2bf(Wn2[k * 128 + n]) : (unsigned short)0;
  }
  for (int i = gid; i < 64 * 32; i += gsz) {
    int n = i >> 5, k = i & 31;
    float v = 0.f;
    if (k < 2)       v = We1[256 * 64 + n];
    else if (k < 4)  v = We1[257 * 64 + n];
    else if (k < 12) v = We1[(258 + (k - 4)) * 64 + n];
    else if (k == 12) v = be1[n];
    else if (k == 13) { float w = We1[256 * 64 + n]; v = w - bf2f(f2bf(w)); }
    else if (k == 14) { float w = We1[257 * 64 + n]; v = w - bf2f(f2bf(w)); }
    else if (k == 15) { float w = be1[n];            v = w - bf2f(f2bf(w)); }
    WrT[i] = (k < 16) ? f2bf(v) : (unsigned short)0;
  }
  if (gid < N_EDGES) atomicAdd(&cnt[eidx[gid]], 1);
}

// ---------------------------------------------------------------------------
// hierarchical scan (coalesced, no per-thread arrays)
// ---------------------------------------------------------------------------
__global__ __launch_bounds__(512) void scan_local(
    const int* __restrict__ cnt, int* __restrict__ rowptr,
    int* __restrict__ bsum)
{
  __shared__ int wsum[8], woff[8];
  const int t = threadIdx.x;
  const int idx = blockIdx.x * 512 + t;
  const int lane = t & 63, wid = t >> 6;
  int c = (idx < N_NODES) ? cnt[idx] : 0;
  int v = c;
  #pragma unroll
  for (int o = 1; o < 64; o <<= 1) {
    int u = __shfl_up(v, o);
    if (lane >= o) v += u;
  }
  if (lane == 63) wsum[wid] = v;
  __syncthreads();
  if (t == 0) {
    int a = 0;
    #pragma unroll
    for (int w = 0; w < 8; ++w) { woff[w] = a; a += wsum[w]; }
    bsum[blockIdx.x] = a;
  }
  __syncthreads();
  if (idx < N_NODES) rowptr[idx] = woff[wid] + (v - c);
}

__global__ __launch_bounds__(128) void scan_mid(
    const int* __restrict__ bsum, int* __restrict__ boff)
{
  __shared__ int ws[2];
  const int t = threadIdx.x;
  const int lane = t & 63, wid = t >> 6;
  int c = (t < SCAN_B) ? bsum[t] : 0;
  int v = c;
  #pragma unroll
  for (int o = 1; o < 64; o <<= 1) {
    int u = __shfl_up(v, o);
    if (lane >= o) v += u;
  }
  if (lane == 63) ws[wid] = v;
  __syncthreads();
  int add = (wid == 1) ? ws[0] : 0;
  if (t < SCAN_B) boff[t] = add + (v - c);
}

__global__ __launch_bounds__(512) void scan_add(
    const int* __restrict__ rowptr, const int* __restrict__ boff,
    int* __restrict__ cursor)
{
  const int idx = blockIdx.x * 512 + threadIdx.x;
  if (idx < N_NODES) cursor[idx] = rowptr[idx] + boff[blockIdx.x];
}

// ---------------------------------------------------------------------------
// fill_reorder (R10): merged fill+reorder. All reads COALESCED per original
// edge (eidx, estruct, erest sequential; xyz 600KB L2-resident gather); gate
// MLP computed here; 36 B of slot data SCATTERED at pos=atomicAdd(cursor).
// Within-node slot order is arbitrary -- aggregation is permutation-invariant.
// Kills the order buffer round trip + one 800k-thread launch.
// ---------------------------------------------------------------------------
__global__ void fill_reorder(
    const int* __restrict__ eidx, const float* __restrict__ xyz,
    const float* __restrict__ estruct, const float* __restrict__ erest,
    int* __restrict__ cursor,
    const float* __restrict__ Wg1, const float* __restrict__ bg1,
    const float* __restrict__ Wg2, const float* __restrict__ bg2,
    float4* __restrict__ metaA, unsigned short* __restrict__ sst,
    int* __restrict__ in_s)
{
  int e = blockIdx.x * 256 + threadIdx.x;
  if (e >= N_EDGES) return;
  int i = eidx[e], j = eidx[N_EDGES + e];
  float dx = xyz[i * 3 + 0] - xyz[j * 3 + 0];
  float dy = xyz[i * 3 + 1] - xyz[j * 3 + 1];
  float dz = xyz[i * 3 + 2] - xyz[j * 3 + 2];
  float d2 = dx * dx + dy * dy + dz * dz;
  float dist = sqrtf(d2 + 1e-9f);
  float rest = erest[e];
  float dl = (dist - rest) / (rest + 1e-9f);
  float4 s0 = *(const float4*)&estruct[e * 8];
  float4 s1 = *(const float4*)&estruct[e * 8 + 4];
  float st[8] = {s0.x, s0.y, s0.z, s0.w, s1.x, s1.y, s1.z, s1.w};
  float gsum = 0.f;
  #pragma unroll
  for (int h = 0; h < 32; ++h) {
    float a = bg1[h] + d2 * Wg1[0 * 32 + h] + dl * Wg1[1 * 32 + h];
    #pragma unroll
    for (int c = 0; c < 8; ++c) a += st[c] * Wg1[(2 + c) * 32 + h];
    gsum += silu_f(a) * Wg2[h];
  }
  float g = sigmoid_f(gsum + bg2[0]);

  int pos = atomicAdd(&cursor[i], 1);
  metaA[pos] = make_float4(d2, dl, g, __int_as_float(j));
  ushort8 w;
  #pragma unroll
  for (int c = 0; c < 8; ++c) w[c] = f2bf(st[c]);
  *(ushort8*)&sst[(long)pos * 8] = w;
  in_s[pos] = i;
}

// ---------------------------------------------------------------------------
// pq: [P|Q] = H @ [We1[0:128] | We1[128:256]], bf16, natural layout.
// Also exports the bf16-converted H tile to Hbf.
// ---------------------------------------------------------------------------
__global__ __launch_bounds__(256, 2) void pq_kernel(
    const float* __restrict__ H, const unsigned short* __restrict__ WpqT,
    unsigned short* __restrict__ P, unsigned short* __restrict__ Q,
    unsigned short* __restrict__ Hbf)
{
  __shared__ unsigned short As[64 * SPQ];
  __shared__ unsigned short Ws[128 * SPQ];

  const int tid  = threadIdx.x;
  const int lane = tid & 63;
  const int wv   = tid >> 6;
  const int lr   = lane & 15;
  const int lq   = lane >> 4;
  const int m0   = wv * 16;
  const int n0   = blockIdx.x * 64;

  for (int i = tid * 8; i < 128 * SPQ; i += 256 * 8)
    *(bf16x8*)&Ws[i] = *(const bf16x8*)&WpqT[i];
  {
    int le = tid >> 2, q = tid & 3;
    int node = n0 + le; if (node >= N_NODES) node = N_NODES - 1;
    const float* src = H + (long)node * 128 + q * 32;
    unsigned short* dst = &As[le * SPQ + q * 32];
    #pragma unroll
    for (int c = 0; c < 32; c += 8) {
      float4 u = *(const float4*)(src + c);
      float4 v = *(const float4*)(src + c + 4);
      *(bf16x8*)(dst + c) = pack8(u, v);
    }
  }
  __syncthreads();

  for (int idx = tid * 8; idx < 64 * 128; idx += 256 * 8) {
    int row = idx >> 7, col = idx & 127;
    *(bf16x8*)&Hbf[((long)n0 + row) * 128 + col] = *(const bf16x8*)&As[row * SPQ + col];
  }

  f32x4 zero4 = {0.f, 0.f, 0.f, 0.f};
  f32x4 acc[8];
  #pragma unroll
  for (int f = 0; f < 8; ++f) acc[f] = zero4;
  #pragma unroll
  for (int s = 0; s < 4; ++s) {
    int kb = s * 32 + lq * 8;
    bf16x8 a = *(const bf16x8*)&As[(m0 + lr) * SPQ + kb];
    #pragma unroll
    for (int f = 0; f < 8; ++f) {
      bf16x8 b = *(const bf16x8*)&Ws[(f * 16 + lr) * SPQ + kb];
      acc[f] = __builtin_amdgcn_mfma_f32_16x16x32_bf16(a, b, acc[f], 0, 0, 0);
    }
  }
  #pragma unroll
  for (int f = 0; f < 8; ++f) {
    #pragma unroll
    for (int r = 0; r < 4; ++r) {
      int node = n0 + m0 + lq * 4 + r;
      if (node < N_NODES) {
        if (f < 4) P[(long)node * 64 + f * 16 + lr] = f2bf(acc[f][r]);
        else       Q[(long)node * 64 + (f - 4) * 16 + lr] = f2bf(acc[f][r]);
      }
    }
  }
}

// ---------------------------------------------------------------------------
// edge_compute (R10): segmented-sum aggregation (R8 structure).
// Changes: ATS 32->40 (fixes 8-way bank conflict on At staging writes,
// the measured 3.65M SQ_LDS_BANK_CONFLICT); Ms stored bf16 (32.7 KB LDS).
// ---------------------------------------------------------------------------
__global__ __launch_bounds__(256, 4) void edge_compute(
    const unsigned short* __restrict__ P, const unsigned short* __restrict__ Q,
    const int* __restrict__ in_s,
    const float4* __restrict__ metaA, const unsigned short* __restrict__ sst,
    const unsigned short* __restrict__ We2T, const float* __restrict__ be2,
    const unsigned short* __restrict__ WrT,
    float* __restrict__ agg)
{
  __shared__ unsigned short W2s[64 * SW2];       // 9.2 KB
  __shared__ unsigned short Es [4 * 16 * SE];    // 9.2 KB
  __shared__ unsigned short At [4 * 16 * ATS];   // 5.1 KB
  __shared__ unsigned short Ms [4 * 16 * MSTR];  // 9.2 KB  (32.7 KB total)

  const int tid  = threadIdx.x;
  const int lane = tid & 63;
  const int wv   = tid >> 6;
  const int lr   = lane & 15;
  const int lq   = lane >> 4;

  for (int i = tid * 8; i < 64 * SW2; i += 256 * 8)
    *(bf16x8*)&W2s[i] = *(const bf16x8*)&We2T[i];

  unsigned short* Es_w = &Es[wv * 16 * SE];
  unsigned short* At_w = &At[wv * 16 * ATS];
  unsigned short* Ms_w = &Ms[wv * 16 * MSTR];

  if (lane < 16) {
    ushort8 z;
    #pragma unroll
    for (int c = 0; c < 8; ++c) z[c] = 0;
    *(ushort8*)&At_w[lane * ATS + 16] = z;
    *(ushort8*)&At_w[lane * ATS + 24] = z;
  }

  bf16x8 aWr[4];
  float bias2[4][4];
  #pragma unroll
  for (int f = 0; f < 4; ++f) {
    aWr[f] = *(const bf16x8*)&WrT[(f * 16 + lr) * 32 + lq * 8];
    #pragma unroll
    for (int r = 0; r < 4; ++r) bias2[f][r] = be2[f * 16 + lq * 4 + r];
  }
  __syncthreads();

  const int n_tiles = N_EDGES / 16;  // 50000
  const int wid = blockIdx.x * 4 + wv;
  const int t0 = wid * EC_CHUNK;
  const int t1 = (t0 + EC_CHUNK < n_tiles) ? (t0 + EC_CHUNK) : n_tiles;
  if (t0 >= n_tiles) return;

  f32x4 zero4 = {0.f, 0.f, 0.f, 0.f};
  int   cur_node   = in_s[t0 * 16];
  float acc        = 0.f;
  bool  use_atomic = true;

  for (int tile = t0; tile < t1; ++tile) {
    const int s0 = tile * 16;

    float4 mm = metaA[s0 + lr];
    int   inode = in_s[s0 + lr];
    int   jnode = __float_as_int(mm.w);
    float g     = mm.z;

    if (lane < 16) {
      ushort8 sv = *(const ushort8*)&sst[(long)(s0 + lane) * 8];
      float d2 = mm.x, dl = mm.y;
      unsigned short d2h = f2bf(d2);
      unsigned short d2l = f2bf(d2 - bf2f(d2h));
      unsigned short dlh = f2bf(dl);
      unsigned short dll = f2bf(dl - bf2f(dlh));
      ushort8 w0, w1;
      w0[0] = d2h;   w0[1] = d2l;   w0[2] = dlh;   w0[3] = dll;
      w0[4] = sv[0]; w0[5] = sv[1]; w0[6] = sv[2]; w0[7] = sv[3];
      w1[0] = sv[4]; w1[1] = sv[5]; w1[2] = sv[6]; w1[3] = sv[7];
      w1[4] = 0x3F80u; w1[5] = d2h; w1[6] = dlh;  w1[7] = 0x3F80u;
      *(ushort8*)&At_w[lane * ATS]     = w0;
      *(ushort8*)&At_w[lane * ATS + 8] = w1;
    }

    bf16x8 bA = *(const bf16x8*)&At_w[lr * ATS + lq * 8];
    f32x4 acc1[4];
    #pragma unroll
    for (int f = 0; f < 4; ++f)
      acc1[f] = __builtin_amdgcn_mfma_f32_16x16x32_bf16(aWr[f], bA, zero4, 0, 0, 0);

    const unsigned short* Pb = P + (long)inode * 64;
    const unsigned short* Qb = Q + (long)jnode * 64;
    #pragma unroll
    for (int f = 0; f < 4; ++f) {
      short4v pv = *(const short4v*)&Pb[f * 16 + lq * 4];
      short4v qv = *(const short4v*)&Qb[f * 16 + lq * 4];
      float v0 = silu_f(bf2f((unsigned short)pv[0]) + bf2f((unsigned short)qv[0]) + acc1[f][0]);
      float v1 = silu_f(bf2f((unsigned short)pv[1]) + bf2f((unsigned short)qv[1]) + acc1[f][1]);
      float v2 = silu_f(bf2f((unsigned short)pv[2]) + bf2f((unsigned short)qv[2]) + acc1[f][2]);
      float v3 = silu_f(bf2f((unsigned short)pv[3]) + bf2f((unsigned short)qv[3]) + acc1[f][3]);
      uint2 w;
      w.x = cvt_pk_bf16(v0, v1);
      w.y = cvt_pk_bf16(v2, v3);
      *(uint2*)&Es_w[lr * SE + f * 16 + lq * 4] = w;
    }

    f32x4 acc2[4];
    #pragma unroll
    for (int f = 0; f < 4; ++f) acc2[f] = zero4;
    #pragma unroll
    for (int s = 0; s < 2; ++s) {
      int kb = s * 32 + lq * 8;
      bf16x8 bE = *(const bf16x8*)&Es_w[lr * SE + kb];
      #pragma unroll
      for (int f = 0; f < 4; ++f) {
        bf16x8 aW = *(const bf16x8*)&W2s[(f * 16 + lr) * SW2 + kb];
        acc2[f] = __builtin_amdgcn_mfma_f32_16x16x32_bf16(aW, bE, acc2[f], 0, 0, 0);
      }
    }

    // epilogue: silu+gate -> wave-private bf16 msg tile [edge][channel]
    #pragma unroll
    for (int f = 0; f < 4; ++f) {
      float o0 = silu_f(acc2[f][0] + bias2[f][0]) * g;
      float o1 = silu_f(acc2[f][1] + bias2[f][1]) * g;
      float o2 = silu_f(acc2[f][2] + bias2[f][2]) * g;
      float o3 = silu_f(acc2[f][3] + bias2[f][3]) * g;
      uint2 w;
      w.x = cvt_pk_bf16(o0, o1);
      w.y = cvt_pk_bf16(o2, o3);
      *(uint2*)&Ms_w[lr * MSTR + f * 16 + lq * 4] = w;
    }

    // segmented sum over the 16 slot-ordered edges (uniform scalar control)
    #pragma unroll
    for (int e = 0; e < 16; ++e) {
      int ie = __builtin_amdgcn_readlane(inode, e);
      if (ie != cur_node) {
        if (use_atomic) atomicAdd(&agg[(long)cur_node * 64 + lane], acc);
        else            agg[(long)cur_node * 64 + lane] = acc;
        use_atomic = false;
        cur_node = ie;
        acc = 0.f;
      }
      acc += bf2f(Ms_w[e * MSTR + lane]);
    }
  }
  atomicAdd(&agg[(long)cur_node * 64 + lane], acc);
}

// ---------------------------------------------------------------------------
// h1_kernel (R10): h1 = silu([Hbf|agg] @ Wn1 + bn1) -> global bf16.
// Weights LDS-RESIDENT: block stages half of Wn1T (55.3 KB, 2-way-free
// stride) once, loops ~3 node tiles. Replaces per-wave 164 KB L2 weight
// streams (513 MB total -> 28 MB) that made node_fused latency-bound.
// ---------------------------------------------------------------------------
__global__ __launch_bounds__(256, 2) void h1_kernel(
    const unsigned short* __restrict__ Hbf, const float* __restrict__ agg,
    const unsigned short* __restrict__ Wn1T, const float* __restrict__ bn1,
    unsigned short* __restrict__ h1)
{
  __shared__ unsigned short Wl[128 * SN1];   // 55.3 KB

  const int tid  = threadIdx.x;
  const int lane = tid & 63;
  const int wv   = tid >> 6;
  const int lr   = lane & 15;
  const int lq   = lane >> 4;
  const int m0   = wv * 16;
  const int p    = blockIdx.x & 1;           // which 128-col half

  for (int i = tid * 8; i < 128 * SN1; i += 256 * 8)
    *(bf16x8*)&Wl[i] = *(const bf16x8*)&Wn1T[p * 128 * SN1 + i];
  __syncthreads();

  f32x4 zero4 = {0.f, 0.f, 0.f, 0.f};
  for (int t = blockIdx.x >> 1; t < NODE_TILES; t += 256) {
    const int n0 = t * 64;
    int rowa = n0 + m0 + lr;
    int rowc = rowa < N_NODES ? rowa : N_NODES - 1;

    f32x4 acc1[8];
    #pragma unroll
    for (int f = 0; f < 8; ++f) acc1[f] = zero4;
    #pragma unroll
    for (int s = 0; s < 6; ++s) {
      int kb = s * 32 + lq * 8;
      bf16x8 a;
      if (s < 4) {
        a = *(const bf16x8*)&Hbf[(long)rowa * 128 + kb];
      } else {
        const float* pp = agg + (long)rowc * 64 + (kb - 128);
        float4 u = *(const float4*)pp;
        float4 v = *(const float4*)(pp + 4);
        a = pack8(u, v);
      }
      #pragma unroll
      for (int f = 0; f < 8; ++f) {
        bf16x8 b = *(const bf16x8*)&Wl[(f * 16 + lr) * SN1 + kb];
        acc1[f] = __builtin_amdgcn_mfma_f32_16x16x32_bf16(a, b, acc1[f], 0, 0, 0);
      }
    }
    #pragma unroll
    for (int f = 0; f < 8; ++f) {
      int col = p * 128 + f * 16 + lr;
      float bias = bn1[col];
      #pragma unroll
      for (int r = 0; r < 4; ++r) {
        int node = n0 + m0 + lq * 4 + r;
        h1[(long)node * 256 + col] = f2bf(silu_f(acc1[f][r] + bias));
      }
    }
  }
}

// ---------------------------------------------------------------------------
// out_kernel (R10): upd = h1 @ Wn2 + bn2; out = LN(H + upd). Wn2T fully
// LDS-resident (71.7 KB) staged once per block; h1 read straight from global
// as contiguous bf16 A-frags (no LDS transpose, no barriers in the loop).
// ---------------------------------------------------------------------------
__global__ __launch_bounds__(256, 2) void out_kernel(
    const float* __restrict__ H, const unsigned short* __restrict__ h1,
    const unsigned short* __restrict__ Wn2T, const float* __restrict__ bn2,
    const float* __restrict__ ln_g, const float* __restrict__ ln_b,
    float* __restrict__ out)
{
  __shared__ unsigned short Wl[128 * SN2];   // 71.7 KB

  const int tid  = threadIdx.x;
  const int lane = tid & 63;
  const int wv   = tid >> 6;
  const int lr   = lane & 15;
  const int lq   = lane >> 4;
  const int m0   = wv * 16;

  for (int i = tid * 8; i < 128 * SN2; i += 256 * 8)
    *(bf16x8*)&Wl[i] = *(const bf16x8*)&Wn2T[i];
  __syncthreads();

  f32x4 zero4 = {0.f, 0.f, 0.f, 0.f};
  for (int t = blockIdx.x; t < NODE_TILES; t += 512) {
    const int n0 = t * 64;
    int rowa = n0 + m0 + lr;

    f32x4 acc2[8];
    #pragma unroll
    for (int f = 0; f < 8; ++f) acc2[f] = zero4;
    #pragma unroll
    for (int s = 0; s < 8; ++s) {
      int kb = s * 32 + lq * 8;
      bf16x8 a = *(const bf16x8*)&h1[(long)rowa * 256 + kb];
      #pragma unroll
      for (int f = 0; f < 8; ++f) {
        bf16x8 b = *(const bf16x8*)&Wl[(f * 16 + lr) * SN2 + kb];
        acc2[f] = __builtin_amdgcn_mfma_f32_16x16x32_bf16(a, b, acc2[f], 0, 0, 0);
      }
    }

    #pragma unroll
    for (int r = 0; r < 4; ++r) {
      int node = n0 + m0 + lq * 4 + r;
      int nc = node < N_NODES ? node : N_NODES - 1;
      float x[8];
      float sum = 0.f, sumsq = 0.f;
      #pragma unroll
      for (int f = 0; f < 8; ++f) {
        int n = f * 16 + lr;
        float u = acc2[f][r] + bn2[n];
        float xv = H[(long)nc * 128 + n] + u;
        x[f] = xv;
        sum += xv;
        sumsq += xv * xv;
      }
      #pragma unroll
      for (int o = 1; o < 16; o <<= 1) {
        sum   += __shfl_xor(sum, o);
        sumsq += __shfl_xor(sumsq, o);
      }
      float mu  = sum * (1.f / 128.f);
      float var = sumsq * (1.f / 128.f) - mu * mu;
      float rstd = rsqrtf(var + 1e-5f);
      if (node < N_NODES) {
        #pragma unroll
        for (int f = 0; f < 8; ++f) {
          int n = f * 16 + lr;
          out[(long)node * 128 + n] = (x[f] - mu) * rstd * ln_g[n] + ln_b[n];
        }
      }
    }
  }
}

extern "C" void kernel_launch(void* const* d_in, const int* in_sizes, int n_in,
                              void* d_out, int out_size, void* d_ws, size_t ws_size,
                              hipStream_t stream) {
  const float* H       = (const float*)d_in[0];
  const float* xyz     = (const float*)d_in[1];
  const int*   eidx    = (const int*)d_in[2];
  const float* estruct = (const float*)d_in[3];
  const float* erest   = (const float*)d_in[4];
  const float* We1     = (const float*)d_in[5];
  const float* be1     = (const float*)d_in[6];
  const float* We2     = (const float*)d_in[7];
  const float* be2     = (const float*)d_in[8];
  const float* Wg1     = (const float*)d_in[9];
  const float* bg1     = (const float*)d_in[10];
  const float* Wg2     = (const float*)d_in[11];
  const float* bg2     = (const float*)d_in[12];
  const float* Wn1     = (const float*)d_in[13];
  const float* bn1     = (const float*)d_in[14];
  const float* Wn2     = (const float*)d_in[15];
  const float* bn2     = (const float*)d_in[16];
  const float* ln_g    = (const float*)d_in[17];
  const float* ln_b    = (const float*)d_in[18];

  char* ws = (char*)d_ws;
  float*          agg    = (float*)(ws + 0);                    //  12,812,288 (50048*64*4)
  unsigned short* Hbf    = (unsigned short*)(ws + 12812288);    //  12,812,288 (50048*128*2)
  float4*         metaA  = (float4*)(ws + 25624576);            //  12,800,000
  unsigned short* sst    = (unsigned short*)(ws + 38424576);    //  12,800,000
  int*            in_s   = (int*)(ws + 51224576);               //   3,200,000
  unsigned short* P      = (unsigned short*)(ws + 54424576);    //   6,400,000
  unsigned short* Qm     = (unsigned short*)(ws + 60824576);    //   6,400,000
  int*            cnt    = (int*)(ws + 67224576);               //     200,192
  int*            rowptr = (int*)(ws + 67424768);               //     200,192 (scan temp)
  int*            cursor = (int*)(ws + 67624960);               //     200,192
  unsigned short* WpqT   = (unsigned short*)(ws + 67825152);    //      34,816
  unsigned short* We2T   = (unsigned short*)(ws + 67859968);    //      11,264 (64*88 pad)
  unsigned short* Wn1T   = (unsigned short*)(ws + 67871232);    //     110,592 (256*216)
  unsigned short* Wn2T   = (unsigned short*)(ws + 67981824);    //      71,680 (128*280)
  unsigned short* WrT    = (unsigned short*)(ws + 68053504);    //       4,096
  int*            bsum   = (int*)(ws + 68057600);               //         512
  int*            boff   = (int*)(ws + 68058112);               //         512
  unsigned short* h1     = (unsigned short*)(ws + 68058624);    //  25,624,576 (50048*256*2)
  float* out = (float*)d_out;

  hipMemsetAsync(cnt, 0, (size_t)N_NODES * sizeof(int), stream);
  hipMemsetAsync(agg, 0, (size_t)50048 * 64 * sizeof(float), stream);

  hipLaunchKernelGGL(prep_hist, dim3(3125), dim3(256), 0, stream,
                     eidx, We1, be1, We2, Wn1, Wn2, WpqT, We2T, Wn1T, Wn2T, WrT, cnt);
  hipLaunchKernelGGL(scan_local, dim3(SCAN_B), dim3(512), 0, stream,
                     cnt, rowptr, bsum);
  hipLaunchKernelGGL(scan_mid, dim3(1), dim3(128), 0, stream,
                     bsum, boff);
  hipLaunchKernelGGL(scan_add, dim3(SCAN_B), dim3(512), 0, stream,
                     rowptr, boff, cursor);
  hipLaunchKernelGGL(fill_reorder, dim3(3125), dim3(256), 0, stream,
                     eidx, xyz, estruct, erest, cursor,
                     Wg1, bg1, Wg2, bg2, metaA, sst, in_s);
  hipLaunchKernelGGL(pq_kernel, dim3(NODE_TILES), dim3(256), 0, stream,
                     H, WpqT, P, Qm, Hbf);
  hipLaunchKernelGGL(edge_compute, dim3(EC_GRID), dim3(256), 0, stream,
                     P, Qm, in_s, metaA, sst, We2T, be2, WrT, agg);
  hipLaunchKernelGGL(h1_kernel, dim3(512), dim3(256), 0, stream,
                     Hbf, agg, Wn1T, bn1, h1);
  hipLaunchKernelGGL(out_kernel, dim3(512), dim3(256), 0, stream,
                     H, h1, Wn2T, bn2, ln_g, ln_b, out);
}

// Round 6
// 368.245 us; speedup vs baseline: 8.2912x; 1.0583x over previous
//
#include <hip/hip_runtime.h>
#include <stdint.h>

#define N_NODES 50000
#define N_EDGES 800000
#define NODE_TILES 782              // ceil(50000/64)

#define SE   72    // e-tile stride (bf16)
#define SW2  72
#define SPQ  136   // pq kernel strides (K=128)
#define SN1  216   // Wn1T row stride (K=192) -- dword 108 == 12 mod 32: 2-way
#define SN2  280   // Wn2T row stride (K=256) -- dword 140 == 12 mod 32: 2-way
#define ATS  40    // edge A-tile row stride (dword 20: 2-way, 16B-aligned)
#define MSTR 72    // msg LDS row stride (bf16)

#define EC_GRID 962   // 962*4 waves * 13 tiles = 50024 >= 50000
#define EC_CHUNK 13

#define SCAN_B 98     // 98*512 = 50176 >= 50000

typedef short bf16x8 __attribute__((ext_vector_type(8)));
typedef short short4v __attribute__((ext_vector_type(4)));
typedef unsigned short ushort8 __attribute__((ext_vector_type(8)));
typedef float f32x4  __attribute__((ext_vector_type(4)));

static __device__ __forceinline__ unsigned short f2bf(float f) {
  unsigned int x = __float_as_uint(f);
  unsigned int r = (x + 0x7fffu + ((x >> 16) & 1u)) >> 16;
  return (unsigned short)r;
}
static __device__ __forceinline__ float bf2f(unsigned short u) {
  return __uint_as_float(((unsigned int)u) << 16);
}
static __device__ __forceinline__ float silu_f(float x) {
  return x * __builtin_amdgcn_rcpf(1.0f + __expf(-x));
}
static __device__ __forceinline__ float sigmoid_f(float x) {
  return __builtin_amdgcn_rcpf(1.0f + __expf(-x));
}
static __device__ __forceinline__ unsigned int cvt_pk_bf16(float lo, float hi) {
  unsigned int r;
  asm("v_cvt_pk_bf16_f32 %0, %1, %2" : "=v"(r) : "v"(lo), "v"(hi));
  return r;
}
static __device__ __forceinline__ bf16x8 pack8(float4 u, float4 v) {
  bf16x8 w;
  w[0] = (short)f2bf(u.x); w[1] = (short)f2bf(u.y);
  w[2] = (short)f2bf(u.z); w[3] = (short)f2bf(u.w);
  w[4] = (short)f2bf(v.x); w[5] = (short)f2bf(v.y);
  w[6] = (short)f2bf(v.z); w[7] = (short)f2bf(v.w);
  return w;
}

// ---------------------------------------------------------------------------
// prep: natural transposed bf16 weights + destination histogram.
// ---------------------------------------------------------------------------
__global__ void prep_hist(
    const int* __restrict__ eidx,
    const float* __restrict__ We1, const float* __restrict__ be1,
    const float* __restrict__ We2,
    const float* __restrict__ Wn1, const float* __restrict__ Wn2,
    unsigned short* __restrict__ WpqT, unsigned short* __restrict__ We2T,
    unsigned short* __restrict__ Wn1T, unsigned short* __restrict__ Wn2T,
    unsigned short* __restrict__ WrT,
    int* __restrict__ cnt)
{
  const int gid = blockIdx.x * 256 + threadIdx.x;
  const int gsz = gridDim.x * 256;
  for (int i = gid; i < 128 * SPQ; i += gsz) {
    int n = i / SPQ, k = i % SPQ;
    unsigned short v = 0;
    if (k < 128) v = (n < 64) ? f2bf(We1[k * 64 + n]) : f2bf(We1[(128 + k) * 64 + (n - 64)]);
    WpqT[i] = v;
  }
  for (int i = gid; i < 64 * SW2; i += gsz) {
    int n = i / SW2, k = i % SW2;
    We2T[i] = (k < 64) ? f2bf(We2[k * 64 + n]) : (unsigned short)0;
  }
  for (int i = gid; i < 256 * SN1; i += gsz) {
    int n = i / SN1, k = i % SN1;
    Wn1T[i] = (k < 192) ? f2bf(Wn1[k * 256 + n]) : (unsigned short)0;
  }
  for (int i = gid; i < 128 * SN2; i += gsz) {
    int n = i / SN2, k = i % SN2;
    Wn2T[i] = (k < 256) ? f2bf(Wn2[k * 128 + n]) : (unsigned short)0;
  }
  for (int i = gid; i < 64 * 32; i += gsz) {
    int n = i >> 5, k = i & 31;
    float v = 0.f;
    if (k < 2)       v = We1[256 * 64 + n];
    else if (k < 4)  v = We1[257 * 64 + n];
    else if (k < 12) v = We1[(258 + (k - 4)) * 64 + n];
    else if (k == 12) v = be1[n];
    else if (k == 13) { float w = We1[256 * 64 + n]; v = w - bf2f(f2bf(w)); }
    else if (k == 14) { float w = We1[257 * 64 + n]; v = w - bf2f(f2bf(w)); }
    else if (k == 15) { float w = be1[n];            v = w - bf2f(f2bf(w)); }
    WrT[i] = (k < 16) ? f2bf(v) : (unsigned short)0;
  }
  if (gid < N_EDGES) atomicAdd(&cnt[eidx[gid]], 1);
}

// ---------------------------------------------------------------------------
// hierarchical scan (coalesced, no per-thread arrays)
// ---------------------------------------------------------------------------
__global__ __launch_bounds__(512) void scan_local(
    const int* __restrict__ cnt, int* __restrict__ rowptr,
    int* __restrict__ bsum)
{
  __shared__ int wsum[8], woff[8];
  const int t = threadIdx.x;
  const int idx = blockIdx.x * 512 + t;
  const int lane = t & 63, wid = t >> 6;
  int c = (idx < N_NODES) ? cnt[idx] : 0;
  int v = c;
  #pragma unroll
  for (int o = 1; o < 64; o <<= 1) {
    int u = __shfl_up(v, o);
    if (lane >= o) v += u;
  }
  if (lane == 63) wsum[wid] = v;
  __syncthreads();
  if (t == 0) {
    int a = 0;
    #pragma unroll
    for (int w = 0; w < 8; ++w) { woff[w] = a; a += wsum[w]; }
    bsum[blockIdx.x] = a;
  }
  __syncthreads();
  if (idx < N_NODES) rowptr[idx] = woff[wid] + (v - c);
}

__global__ __launch_bounds__(128) void scan_mid(
    const int* __restrict__ bsum, int* __restrict__ boff)
{
  __shared__ int ws[2];
  const int t = threadIdx.x;
  const int lane = t & 63, wid = t >> 6;
  int c = (t < SCAN_B) ? bsum[t] : 0;
  int v = c;
  #pragma unroll
  for (int o = 1; o < 64; o <<= 1) {
    int u = __shfl_up(v, o);
    if (lane >= o) v += u;
  }
  if (lane == 63) ws[wid] = v;
  __syncthreads();
  int add = (wid == 1) ? ws[0] : 0;
  if (t < SCAN_B) boff[t] = add + (v - c);
}

// scan_add also zeroes agg (folds the 12.8 MB memset dispatch away)
__global__ __launch_bounds__(512) void scan_add(
    const int* __restrict__ rowptr, const int* __restrict__ boff,
    int* __restrict__ cursor, float4* __restrict__ agg)
{
  const int idx = blockIdx.x * 512 + threadIdx.x;
  if (idx < N_NODES) cursor[idx] = rowptr[idx] + boff[blockIdx.x];
  if (idx < 50048) {
    float4 z = make_float4(0.f, 0.f, 0.f, 0.f);
    float4* p = agg + (long)idx * 16;
    #pragma unroll
    for (int k = 0; k < 16; ++k) p[k] = z;
  }
}

// ---------------------------------------------------------------------------
// fill_reorder (R11): scatters ONE 32-byte record per slot (was 36 B across
// 3 buffers = 3 partial-line RMWs -> measured 102 MB WRITE). Record layout:
//   [0:8)   d2h,d2l,dlh,dll   (split-precision bf16, precomputed here)
//   [8:24)  struct st[0..7] bf16
//   [24:28) g f32
//   [28:32) i | j<<16        (ushort node ids, N=50000 < 65536)
// Bytes [0:16) are verbatim the edge A-tile w0 row for edge_compute.
// ---------------------------------------------------------------------------
__global__ void fill_reorder(
    const int* __restrict__ eidx, const float* __restrict__ xyz,
    const float* __restrict__ estruct, const float* __restrict__ erest,
    int* __restrict__ cursor,
    const float* __restrict__ Wg1, const float* __restrict__ bg1,
    const float* __restrict__ Wg2, const float* __restrict__ bg2,
    unsigned short* __restrict__ rec)
{
  int e = blockIdx.x * 256 + threadIdx.x;
  if (e >= N_EDGES) return;
  int i = eidx[e], j = eidx[N_EDGES + e];
  float dx = xyz[i * 3 + 0] - xyz[j * 3 + 0];
  float dy = xyz[i * 3 + 1] - xyz[j * 3 + 1];
  float dz = xyz[i * 3 + 2] - xyz[j * 3 + 2];
  float d2 = dx * dx + dy * dy + dz * dz;
  float dist = sqrtf(d2 + 1e-9f);
  float rest = erest[e];
  float dl = (dist - rest) / (rest + 1e-9f);
  float4 s0 = *(const float4*)&estruct[e * 8];
  float4 s1 = *(const float4*)&estruct[e * 8 + 4];
  float st[8] = {s0.x, s0.y, s0.z, s0.w, s1.x, s1.y, s1.z, s1.w};
  float gsum = 0.f;
  #pragma unroll
  for (int h = 0; h < 32; ++h) {
    float a = bg1[h] + d2 * Wg1[0 * 32 + h] + dl * Wg1[1 * 32 + h];
    #pragma unroll
    for (int c = 0; c < 8; ++c) a += st[c] * Wg1[(2 + c) * 32 + h];
    gsum += silu_f(a) * Wg2[h];
  }
  float g = sigmoid_f(gsum + bg2[0]);

  unsigned short d2h = f2bf(d2);
  unsigned short d2l = f2bf(d2 - bf2f(d2h));
  unsigned short dlh = f2bf(dl);
  unsigned short dll = f2bf(dl - bf2f(dlh));

  ushort8 w0;
  w0[0] = d2h; w0[1] = d2l; w0[2] = dlh; w0[3] = dll;
  w0[4] = f2bf(st[0]); w0[5] = f2bf(st[1]); w0[6] = f2bf(st[2]); w0[7] = f2bf(st[3]);
  uint4 w1;
  w1.x = (unsigned int)f2bf(st[4]) | ((unsigned int)f2bf(st[5]) << 16);
  w1.y = (unsigned int)f2bf(st[6]) | ((unsigned int)f2bf(st[7]) << 16);
  w1.z = __float_as_uint(g);
  w1.w = (unsigned int)i | ((unsigned int)j << 16);

  int pos = atomicAdd(&cursor[i], 1);
  unsigned short* dst = rec + (long)pos * 16;
  *(ushort8*)dst = w0;
  *(uint4*)(dst + 8) = w1;
}

// ---------------------------------------------------------------------------
// pq (R11): persistent blocks -- weights staged ONCE, loop over node tiles.
// [P|Q] = H @ [We1[0:128] | We1[128:256]]; exports bf16 H tile to Hbf.
// ---------------------------------------------------------------------------
__global__ __launch_bounds__(256, 2) void pq_kernel(
    const float* __restrict__ H, const unsigned short* __restrict__ WpqT,
    unsigned short* __restrict__ P, unsigned short* __restrict__ Q,
    unsigned short* __restrict__ Hbf)
{
  __shared__ unsigned short As[64 * SPQ];
  __shared__ unsigned short Ws[128 * SPQ];

  const int tid  = threadIdx.x;
  const int lane = tid & 63;
  const int wv   = tid >> 6;
  const int lr   = lane & 15;
  const int lq   = lane >> 4;
  const int m0   = wv * 16;

  for (int i = tid * 8; i < 128 * SPQ; i += 256 * 8)
    *(bf16x8*)&Ws[i] = *(const bf16x8*)&WpqT[i];

  f32x4 zero4 = {0.f, 0.f, 0.f, 0.f};
  for (int t = blockIdx.x; t < NODE_TILES; t += 512) {
    const int n0 = t * 64;
    __syncthreads();   // protect As from previous iteration's readers
    {
      int le = tid >> 2, q = tid & 3;
      int node = n0 + le; if (node >= N_NODES) node = N_NODES - 1;
      const float* src = H + (long)node * 128 + q * 32;
      unsigned short* dst = &As[le * SPQ + q * 32];
      #pragma unroll
      for (int c = 0; c < 32; c += 8) {
        float4 u = *(const float4*)(src + c);
        float4 v = *(const float4*)(src + c + 4);
        *(bf16x8*)(dst + c) = pack8(u, v);
      }
    }
    __syncthreads();

    for (int idx = tid * 8; idx < 64 * 128; idx += 256 * 8) {
      int row = idx >> 7, col = idx & 127;
      *(bf16x8*)&Hbf[((long)n0 + row) * 128 + col] = *(const bf16x8*)&As[row * SPQ + col];
    }

    f32x4 acc[8];
    #pragma unroll
    for (int f = 0; f < 8; ++f) acc[f] = zero4;
    #pragma unroll
    for (int s = 0; s < 4; ++s) {
      int kb = s * 32 + lq * 8;
      bf16x8 a = *(const bf16x8*)&As[(m0 + lr) * SPQ + kb];
      #pragma unroll
      for (int f = 0; f < 8; ++f) {
        bf16x8 b = *(const bf16x8*)&Ws[(f * 16 + lr) * SPQ + kb];
        acc[f] = __builtin_amdgcn_mfma_f32_16x16x32_bf16(a, b, acc[f], 0, 0, 0);
      }
    }
    #pragma unroll
    for (int f = 0; f < 8; ++f) {
      #pragma unroll
      for (int r = 0; r < 4; ++r) {
        int node = n0 + m0 + lq * 4 + r;
        if (node < N_NODES) {
          if (f < 4) P[(long)node * 64 + f * 16 + lr] = f2bf(acc[f][r]);
          else       Q[(long)node * 64 + (f - 4) * 16 + lr] = f2bf(acc[f][r]);
        }
      }
    }
  }
}

// ---------------------------------------------------------------------------
// edge_compute (R11): single 32B-record stream (replaces metaA+sst+in_s);
// d2/dl splits precomputed; i,j unpacked from ushort pair. Segmented-sum
// aggregation unchanged (R8 structure).
// ---------------------------------------------------------------------------
__global__ __launch_bounds__(256, 4) void edge_compute(
    const unsigned short* __restrict__ P, const unsigned short* __restrict__ Q,
    const unsigned short* __restrict__ rec,
    const unsigned short* __restrict__ We2T, const float* __restrict__ be2,
    const unsigned short* __restrict__ WrT,
    float* __restrict__ agg)
{
  __shared__ unsigned short W2s[64 * SW2];       // 9.2 KB
  __shared__ unsigned short Es [4 * 16 * SE];    // 9.2 KB
  __shared__ unsigned short At [4 * 16 * ATS];   // 5.1 KB
  __shared__ unsigned short Ms [4 * 16 * MSTR];  // 9.2 KB  (32.7 KB total)

  const int tid  = threadIdx.x;
  const int lane = tid & 63;
  const int wv   = tid >> 6;
  const int lr   = lane & 15;
  const int lq   = lane >> 4;

  for (int i = tid * 8; i < 64 * SW2; i += 256 * 8)
    *(bf16x8*)&W2s[i] = *(const bf16x8*)&We2T[i];

  unsigned short* Es_w = &Es[wv * 16 * SE];
  unsigned short* At_w = &At[wv * 16 * ATS];
  unsigned short* Ms_w = &Ms[wv * 16 * MSTR];

  if (lane < 16) {
    ushort8 z;
    #pragma unroll
    for (int c = 0; c < 8; ++c) z[c] = 0;
    *(ushort8*)&At_w[lane * ATS + 16] = z;
    *(ushort8*)&At_w[lane * ATS + 24] = z;
  }

  bf16x8 aWr[4];
  float bias2[4][4];
  #pragma unroll
  for (int f = 0; f < 4; ++f) {
    aWr[f] = *(const bf16x8*)&WrT[(f * 16 + lr) * 32 + lq * 8];
    #pragma unroll
    for (int r = 0; r < 4; ++r) bias2[f][r] = be2[f * 16 + lq * 4 + r];
  }
  __syncthreads();

  const int n_tiles = N_EDGES / 16;  // 50000
  const int wid = blockIdx.x * 4 + wv;
  const int t0 = wid * EC_CHUNK;
  const int t1 = (t0 + EC_CHUNK < n_tiles) ? (t0 + EC_CHUNK) : n_tiles;
  if (t0 >= n_tiles) return;

  f32x4 zero4 = {0.f, 0.f, 0.f, 0.f};
  int   cur_node;
  {
    int ij0 = *(const int*)(rec + (long)t0 * 16 * 16 + 14);
    cur_node = ij0 & 0xffff;
  }
  float acc        = 0.f;
  bool  use_atomic = true;

  for (int tile = t0; tile < t1; ++tile) {
    const int s0 = tile * 16;

    const unsigned short* rp = rec + (long)(s0 + lr) * 16;
    ushort8 ra = *(const ushort8*)rp;          // d2h,d2l,dlh,dll,st0..3
    uint4   rb = *(const uint4*)(rp + 8);      // st4..7 | g | i,j
    float g     = __uint_as_float(rb.z);
    int   inode = rb.w & 0xffff;
    int   jnode = (rb.w >> 16) & 0xffff;

    if (lane < 16) {
      ushort8 w1;
      w1[0] = (unsigned short)(rb.x & 0xffff);
      w1[1] = (unsigned short)(rb.x >> 16);
      w1[2] = (unsigned short)(rb.y & 0xffff);
      w1[3] = (unsigned short)(rb.y >> 16);
      w1[4] = 0x3F80u; w1[5] = (unsigned short)ra[0];
      w1[6] = (unsigned short)ra[2]; w1[7] = 0x3F80u;
      *(ushort8*)&At_w[lane * ATS]     = ra;
      *(ushort8*)&At_w[lane * ATS + 8] = w1;
    }

    bf16x8 bA = *(const bf16x8*)&At_w[lr * ATS + lq * 8];
    f32x4 acc1[4];
    #pragma unroll
    for (int f = 0; f < 4; ++f)
      acc1[f] = __builtin_amdgcn_mfma_f32_16x16x32_bf16(aWr[f], bA, zero4, 0, 0, 0);

    const unsigned short* Pb = P + (long)inode * 64;
    const unsigned short* Qb = Q + (long)jnode * 64;
    #pragma unroll
    for (int f = 0; f < 4; ++f) {
      short4v pv = *(const short4v*)&Pb[f * 16 + lq * 4];
      short4v qv = *(const short4v*)&Qb[f * 16 + lq * 4];
      float v0 = silu_f(bf2f((unsigned short)pv[0]) + bf2f((unsigned short)qv[0]) + acc1[f][0]);
      float v1 = silu_f(bf2f((unsigned short)pv[1]) + bf2f((unsigned short)qv[1]) + acc1[f][1]);
      float v2 = silu_f(bf2f((unsigned short)pv[2]) + bf2f((unsigned short)qv[2]) + acc1[f][2]);
      float v3 = silu_f(bf2f((unsigned short)pv[3]) + bf2f((unsigned short)qv[3]) + acc1[f][3]);
      uint2 w;
      w.x = cvt_pk_bf16(v0, v1);
      w.y = cvt_pk_bf16(v2, v3);
      *(uint2*)&Es_w[lr * SE + f * 16 + lq * 4] = w;
    }

    f32x4 acc2[4];
    #pragma unroll
    for (int f = 0; f < 4; ++f) acc2[f] = zero4;
    #pragma unroll
    for (int s = 0; s < 2; ++s) {
      int kb = s * 32 + lq * 8;
      bf16x8 bE = *(const bf16x8*)&Es_w[lr * SE + kb];
      #pragma unroll
      for (int f = 0; f < 4; ++f) {
        bf16x8 aW = *(const bf16x8*)&W2s[(f * 16 + lr) * SW2 + kb];
        acc2[f] = __builtin_amdgcn_mfma_f32_16x16x32_bf16(aW, bE, acc2[f], 0, 0, 0);
      }
    }

    // epilogue: silu+gate -> wave-private bf16 msg tile [edge][channel]
    #pragma unroll
    for (int f = 0; f < 4; ++f) {
      float o0 = silu_f(acc2[f][0] + bias2[f][0]) * g;
      float o1 = silu_f(acc2[f][1] + bias2[f][1]) * g;
      float o2 = silu_f(acc2[f][2] + bias2[f][2]) * g;
      float o3 = silu_f(acc2[f][3] + bias2[f][3]) * g;
      uint2 w;
      w.x = cvt_pk_bf16(o0, o1);
      w.y = cvt_pk_bf16(o2, o3);
      *(uint2*)&Ms_w[lr * MSTR + f * 16 + lq * 4] = w;
    }

    // segmented sum over the 16 slot-ordered edges (uniform scalar control)
    #pragma unroll
    for (int e = 0; e < 16; ++e) {
      int ie = __builtin_amdgcn_readlane(inode, e);
      if (ie != cur_node) {
        if (use_atomic) atomicAdd(&agg[(long)cur_node * 64 + lane], acc);
        else            agg[(long)cur_node * 64 + lane] = acc;
        use_atomic = false;
        cur_node = ie;
        acc = 0.f;
      }
      acc += bf2f(Ms_w[e * MSTR + lane]);
    }
  }
  atomicAdd(&agg[(long)cur_node * 64 + lane], acc);
}

// ---------------------------------------------------------------------------
// h1_kernel: h1 = silu([Hbf|agg] @ Wn1 + bn1) -> global bf16. Half of Wn1T
// LDS-resident per block (55.3 KB), persistent loop.
// ---------------------------------------------------------------------------
__global__ __launch_bounds__(256, 2) void h1_kernel(
    const unsigned short* __restrict__ Hbf, const float* __restrict__ agg,
    const unsigned short* __restrict__ Wn1T, const float* __restrict__ bn1,
    unsigned short* __restrict__ h1)
{
  __shared__ unsigned short Wl[128 * SN1];   // 55.3 KB

  const int tid  = threadIdx.x;
  const int lane = tid & 63;
  const int wv   = tid >> 6;
  const int lr   = lane & 15;
  const int lq   = lane >> 4;
  const int m0   = wv * 16;
  const int p    = blockIdx.x & 1;           // which 128-col half

  for (int i = tid * 8; i < 128 * SN1; i += 256 * 8)
    *(bf16x8*)&Wl[i] = *(const bf16x8*)&Wn1T[p * 128 * SN1 + i];
  __syncthreads();

  f32x4 zero4 = {0.f, 0.f, 0.f, 0.f};
  for (int t = blockIdx.x >> 1; t < NODE_TILES; t += 256) {
    const int n0 = t * 64;
    int rowa = n0 + m0 + lr;
    int rowc = rowa < N_NODES ? rowa : N_NODES - 1;

    f32x4 acc1[8];
    #pragma unroll
    for (int f = 0; f < 8; ++f) acc1[f] = zero4;
    #pragma unroll
    for (int s = 0; s < 6; ++s) {
      int kb = s * 32 + lq * 8;
      bf16x8 a;
      if (s < 4) {
        a = *(const bf16x8*)&Hbf[(long)rowa * 128 + kb];
      } else {
        const float* pp = agg + (long)rowc * 64 + (kb - 128);
        float4 u = *(const float4*)pp;
        float4 v = *(const float4*)(pp + 4);
        a = pack8(u, v);
      }
      #pragma unroll
      for (int f = 0; f < 8; ++f) {
        bf16x8 b = *(const bf16x8*)&Wl[(f * 16 + lr) * SN1 + kb];
        acc1[f] = __builtin_amdgcn_mfma_f32_16x16x32_bf16(a, b, acc1[f], 0, 0, 0);
      }
    }
    #pragma unroll
    for (int f = 0; f < 8; ++f) {
      int col = p * 128 + f * 16 + lr;
      float bias = bn1[col];
      #pragma unroll
      for (int r = 0; r < 4; ++r) {
        int node = n0 + m0 + lq * 4 + r;
        h1[(long)node * 256 + col] = f2bf(silu_f(acc1[f][r] + bias));
      }
    }
  }
}

// ---------------------------------------------------------------------------
// out_kernel: upd = h1 @ Wn2 + bn2; out = LN(H + upd). Wn2T LDS-resident.
// ---------------------------------------------------------------------------
__global__ __launch_bounds__(256, 2) void out_kernel(
    const float* __restrict__ H, const unsigned short* __restrict__ h1,
    const unsigned short* __restrict__ Wn2T, const float* __restrict__ bn2,
    const float* __restrict__ ln_g, const float* __restrict__ ln_b,
    float* __restrict__ out)
{
  __shared__ unsigned short Wl[128 * SN2];   // 71.7 KB

  const int tid  = threadIdx.x;
  const int lane = tid & 63;
  const int wv   = tid >> 6;
  const int lr   = lane & 15;
  const int lq   = lane >> 4;
  const int m0   = wv * 16;

  for (int i = tid * 8; i < 128 * SN2; i += 256 * 8)
    *(bf16x8*)&Wl[i] = *(const bf16x8*)&Wn2T[i];
  __syncthreads();

  f32x4 zero4 = {0.f, 0.f, 0.f, 0.f};
  for (int t = blockIdx.x; t < NODE_TILES; t += 512) {
    const int n0 = t * 64;
    int rowa = n0 + m0 + lr;

    f32x4 acc2[8];
    #pragma unroll
    for (int f = 0; f < 8; ++f) acc2[f] = zero4;
    #pragma unroll
    for (int s = 0; s < 8; ++s) {
      int kb = s * 32 + lq * 8;
      bf16x8 a = *(const bf16x8*)&h1[(long)rowa * 256 + kb];
      #pragma unroll
      for (int f = 0; f < 8; ++f) {
        bf16x8 b = *(const bf16x8*)&Wl[(f * 16 + lr) * SN2 + kb];
        acc2[f] = __builtin_amdgcn_mfma_f32_16x16x32_bf16(a, b, acc2[f], 0, 0, 0);
      }
    }

    #pragma unroll
    for (int r = 0; r < 4; ++r) {
      int node = n0 + m0 + lq * 4 + r;
      int nc = node < N_NODES ? node : N_NODES - 1;
      float x[8];
      float sum = 0.f, sumsq = 0.f;
      #pragma unroll
      for (int f = 0; f < 8; ++f) {
        int n = f * 16 + lr;
        float u = acc2[f][r] + bn2[n];
        float xv = H[(long)nc * 128 + n] + u;
        x[f] = xv;
        sum += xv;
        sumsq += xv * xv;
      }
      #pragma unroll
      for (int o = 1; o < 16; o <<= 1) {
        sum   += __shfl_xor(sum, o);
        sumsq += __shfl_xor(sumsq, o);
      }
      float mu  = sum * (1.f / 128.f);
      float var = sumsq * (1.f / 128.f) - mu * mu;
      float rstd = rsqrtf(var + 1e-5f);
      if (node < N_NODES) {
        #pragma unroll
        for (int f = 0; f < 8; ++f) {
          int n = f * 16 + lr;
          out[(long)node * 128 + n] = (x[f] - mu) * rstd * ln_g[n] + ln_b[n];
        }
      }
    }
  }
}

extern "C" void kernel_launch(void* const* d_in, const int* in_sizes, int n_in,
                              void* d_out, int out_size, void* d_ws, size_t ws_size,
                              hipStream_t stream) {
  const float* H       = (const float*)d_in[0];
  const float* xyz     = (const float*)d_in[1];
  const int*   eidx    = (const int*)d_in[2];
  const float* estruct = (const float*)d_in[3];
  const float* erest   = (const float*)d_in[4];
  const float* We1     = (const float*)d_in[5];
  const float* be1     = (const float*)d_in[6];
  const float* We2     = (const float*)d_in[7];
  const float* be2     = (const float*)d_in[8];
  const float* Wg1     = (const float*)d_in[9];
  const float* bg1     = (const float*)d_in[10];
  const float* Wg2     = (const float*)d_in[11];
  const float* bg2     = (const float*)d_in[12];
  const float* Wn1     = (const float*)d_in[13];
  const float* bn1     = (const float*)d_in[14];
  const float* Wn2     = (const float*)d_in[15];
  const float* bn2     = (const float*)d_in[16];
  const float* ln_g    = (const float*)d_in[17];
  const float* ln_b    = (const float*)d_in[18];

  char* ws = (char*)d_ws;
  float*          agg    = (float*)(ws + 0);                    //  12,812,288 (50048*64*4)
  unsigned short* Hbf    = (unsigned short*)(ws + 12812288);    //  12,812,288 (50048*128*2)
  unsigned short* rec    = (unsigned short*)(ws + 25624576);    //  25,600,000 (800000*32)
  unsigned short* P      = (unsigned short*)(ws + 51224576);    //   6,400,000
  unsigned short* Qm     = (unsigned short*)(ws + 57624576);    //   6,400,000
  int*            cnt    = (int*)(ws + 64024576);               //     200,192
  int*            rowptr = (int*)(ws + 64224768);               //     200,192 (scan temp)
  int*            cursor = (int*)(ws + 64424960);               //     200,192
  unsigned short* WpqT   = (unsigned short*)(ws + 64625152);    //      34,816
  unsigned short* We2T   = (unsigned short*)(ws + 64659968);    //       9,216
  unsigned short* Wn1T   = (unsigned short*)(ws + 64669184);    //     110,592 (256*216)
  unsigned short* Wn2T   = (unsigned short*)(ws + 64779776);    //      71,680 (128*280)
  unsigned short* WrT    = (unsigned short*)(ws + 64851456);    //       4,096
  int*            bsum   = (int*)(ws + 64855552);               //         512
  int*            boff   = (int*)(ws + 64856064);               //         512
  unsigned short* h1     = (unsigned short*)(ws + 64856576);    //  25,624,576 (50048*256*2)
  float* out = (float*)d_out;

  hipMemsetAsync(cnt, 0, (size_t)N_NODES * sizeof(int), stream);

  hipLaunchKernelGGL(prep_hist, dim3(3125), dim3(256), 0, stream,
                     eidx, We1, be1, We2, Wn1, Wn2, WpqT, We2T, Wn1T, Wn2T, WrT, cnt);
  hipLaunchKernelGGL(scan_local, dim3(SCAN_B), dim3(512), 0, stream,
                     cnt, rowptr, bsum);
  hipLaunchKernelGGL(scan_mid, dim3(1), dim3(128), 0, stream,
                     bsum, boff);
  hipLaunchKernelGGL(scan_add, dim3(SCAN_B), dim3(512), 0, stream,
                     rowptr, boff, cursor, (float4*)agg);
  hipLaunchKernelGGL(fill_reorder, dim3(3125), dim3(256), 0, stream,
                     eidx, xyz, estruct, erest, cursor,
                     Wg1, bg1, Wg2, bg2, rec);
  hipLaunchKernelGGL(pq_kernel, dim3(512), dim3(256), 0, stream,
                     H, WpqT, P, Qm, Hbf);
  hipLaunchKernelGGL(edge_compute, dim3(EC_GRID), dim3(256), 0, stream,
                     P, Qm, rec, We2T, be2, WrT, agg);
  hipLaunchKernelGGL(h1_kernel, dim3(512), dim3(256), 0, stream,
                     Hbf, agg, Wn1T, bn1, h1);
  hipLaunchKernelGGL(out_kernel, dim3(512), dim3(256), 0, stream,
                     H, h1, Wn2T, bn2, ln_g, ln_b, out);
}